// Round 10
// baseline (1214.535 us; speedup 1.0000x reference)
//
#include <hip/hip_runtime.h>
#include <math.h>

// Problem constants (from reference)
#define V_SZ 32000
#define D_SZ 1024
#define H_SZ 16
#define L_SZ 4
#define F_SZ 4096
#define S_SZ 1024
#define B_SZ 2
#define DK 64              // D/H
#define NTOK (B_SZ * S_SZ) // 2048
#define NEG_INF -3.0e38f

typedef _Float16 half8 __attribute__((ext_vector_type(8)));
typedef _Float16 half4 __attribute__((ext_vector_type(4)));
typedef float floatx4 __attribute__((ext_vector_type(4)));

// async global->LDS, 16B per lane; lds dest is wave-uniform base + lane*16.
__device__ __forceinline__ void gload16(const void* g, void* l) {
    __builtin_amdgcn_global_load_lds(
        (const __attribute__((address_space(1))) unsigned int*)g,
        (__attribute__((address_space(3))) unsigned int*)l, 16, 0, 0);
}

// ---------------------------------------------------------------------------
// fp32 -> fp16 conversion: all 7 per-layer weight mats in one launch.
// ---------------------------------------------------------------------------
__global__ __launch_bounds__(256) void f2h7(const float* __restrict__ sq,
                                            const float* __restrict__ sk,
                                            const float* __restrict__ sv,
                                            const float* __restrict__ so,
                                            const float* __restrict__ s1,
                                            const float* __restrict__ s3,
                                            const float* __restrict__ s2,
                                            _Float16* __restrict__ d,
                                            int nDD8, int nFD8) {
    const int i = blockIdx.x * 256 + threadIdx.x;
    const float* s;
    int off;
    if (i < 4 * nDD8) {
        const int sel = i / nDD8;
        off = i - sel * nDD8;
        s = sel == 0 ? sq : (sel == 1 ? sk : (sel == 2 ? sv : so));
    } else {
        const int j = i - 4 * nDD8;
        const int sel = j / nFD8;
        off = j - sel * nFD8;
        s = sel == 0 ? s1 : (sel == 1 ? s3 : s2);
    }
    const float4 a = ((const float4*)s)[2 * off];
    const float4 b = ((const float4*)s)[2 * off + 1];
    half8 h = {(_Float16)a.x, (_Float16)a.y, (_Float16)a.z, (_Float16)a.w,
               (_Float16)b.x, (_Float16)b.y, (_Float16)b.z, (_Float16)b.w};
    ((half8*)d)[i] = h;
}

__global__ __launch_bounds__(256) void f2h(const float* __restrict__ in,
                                           _Float16* __restrict__ out, int n8) {
    const int i = blockIdx.x * 256 + threadIdx.x;
    if (i >= n8) return;
    const float4 a = ((const float4*)in)[2 * i];
    const float4 b = ((const float4*)in)[2 * i + 1];
    half8 h = {(_Float16)a.x, (_Float16)a.y, (_Float16)a.z, (_Float16)a.w,
               (_Float16)b.x, (_Float16)b.y, (_Float16)b.z, (_Float16)b.w};
    ((half8*)out)[i] = h;
}

// ---------------------------------------------------------------------------
// Embedding gather (fp32)
// ---------------------------------------------------------------------------
__global__ __launch_bounds__(256) void embed_kernel(const int* __restrict__ ids,
                                                    const float* __restrict__ emb,
                                                    float* __restrict__ x) {
    const int row = blockIdx.x;
    const int id = ids[row];
    const float4* src = (const float4*)(emb + (size_t)id * D_SZ);
    float4* dst = (float4*)(x + (size_t)row * D_SZ);
    dst[threadIdx.x] = src[threadIdx.x];
}

// ---------------------------------------------------------------------------
// RMSNorm: fp32 in, fp16 out
// ---------------------------------------------------------------------------
__global__ __launch_bounds__(256) void rmsnorm_kernel(const float* __restrict__ x,
                                                      const float* __restrict__ w,
                                                      _Float16* __restrict__ out) {
    const int row = blockIdx.x;
    const int tid = threadIdx.x;
    const float4 v = ((const float4*)(x + (size_t)row * D_SZ))[tid];
    float ss = v.x * v.x + v.y * v.y + v.z * v.z + v.w * v.w;
#pragma unroll
    for (int off = 32; off > 0; off >>= 1) ss += __shfl_down(ss, off, 64);
    __shared__ float red[4];
    if ((tid & 63) == 0) red[tid >> 6] = ss;
    __syncthreads();
    const float tot = red[0] + red[1] + red[2] + red[3];
    const float inv = 1.0f / (sqrtf(tot * (1.0f / (float)D_SZ)) + 1e-5f);
    const float4 wv = ((const float4*)w)[tid];
    half4 o = {(_Float16)(v.x * inv * wv.x), (_Float16)(v.y * inv * wv.y),
               (_Float16)(v.z * inv * wv.z), (_Float16)(v.w * inv * wv.w)};
    ((half4*)(out + (size_t)row * D_SZ))[tid] = o;
}

// ---------------------------------------------------------------------------
// 8-phase deep-pipelined 256x256 MFMA fp16 GEMM (NT), faithful T3+T4 port.
// BK=64 split into K-halves; halves {A.k0,B.k0,A.k1,B.k1} are contiguous
// 16 KB LDS sub-arrays (linear global_load_lds). Per K-tile 4 phases:
//   {ds_read quadrant | stage 1 half | barrier | lgkmcnt(0)+sched_barrier |
//    setprio(1) 16 MFMA setprio(0) | barrier}
// Stage plan: q0->(t+1).A.k1, q1->(t+1).B.k1, q2->(t+2).A.k0, q3->(t+2).B.k0
// Counted vmcnt(4) once per tile boundary (0 only at the final tile).
// LDS XOR swizzle chunk ^= (row>>1)&3 on 64B rows, both-sides.
//   (row&1 selects the bank group, so the XOR must use bits >=1 of row;
//    verified 0-conflict in round 6 with this exact pattern.)
// Requires M%256==0, N%256==0, K%64==0, K>=128.
// ---------------------------------------------------------------------------
template <bool MFAST>
__global__ __launch_bounds__(512) void hgemm8p(const _Float16* __restrict__ A,
                                               const _Float16* __restrict__ B,
                                               float* __restrict__ Cf,
                                               int M, int N, int K) {
    __shared__ __align__(16) _Float16 As[2][2][256 * 32];
    __shared__ __align__(16) _Float16 Bs[2][2][256 * 32];
    const int tid = threadIdx.x;
    const int lane = tid & 63, wave = tid >> 6;
    const int wm = wave >> 2, wn = wave & 3;
    const int l15 = lane & 15, g = lane >> 4;

    // bijective XCD chunk swizzle (m204)
    const int gm = M >> 8, gn = N >> 8, nwg = gm * gn;
    const int orig = blockIdx.x;
    const int q8 = nwg >> 3, r8 = nwg & 7, xcd = orig & 7, j8 = orig >> 3;
    const int wgid = (xcd < r8 ? xcd * (q8 + 1) : r8 * (q8 + 1) + (xcd - r8) * q8) + j8;
    const int bm = MFAST ? (wgid % gm) : (wgid / gn);
    const int bn = MFAST ? (wgid / gm) : (wgid % gn);
    const int m0 = bm << 8, n0 = bn << 8;

    // staging geometry: half = 256 rows x 32 K (64 B) = 16 KB = 2 gloads.
    // gload r: row = r*128 + tid/4, phys chunk p = tid&3 holds logical
    // chunk c = p ^ ((row>>1)&3) -> source byte col = c*16 within the half.
    const int rowS = tid >> 2;                              // 0..127
    const int srcC = ((tid & 3) ^ ((rowS >> 1) & 3)) << 4;  // inv-swizzled src
    const size_t Kb = (size_t)K * 2;
    const char* gA = (const char*)A + (size_t)(m0 + rowS) * Kb + srcC;
    const char* gB = (const char*)B + (size_t)(n0 + rowS) * Kb + srcC;
    const size_t g128 = 128 * Kb;                    // +128 rows

#define STA(ks, t, buf) do {                                              \
        const char* _s = gA + (size_t)(t) * 128 + (ks) * 64;              \
        char* _d = (char*)&As[buf][ks][0];                                \
        gload16(_s, _d + tid * 16);                                       \
        gload16(_s + g128, _d + 8192 + tid * 16);                         \
    } while (0)
#define STB(ks, t, buf) do {                                              \
        const char* _s = gB + (size_t)(t) * 128 + (ks) * 64;              \
        char* _d = (char*)&Bs[buf][ks][0];                                \
        gload16(_s, _d + tid * 16);                                       \
        gload16(_s + g128, _d + 8192 + tid * 16);                         \
    } while (0)

    half8 aF[8], bF[2];
#define READA(buf, ks) do {                                               \
        _Pragma("unroll")                                                 \
        for (int i = 0; i < 8; i++) {                                     \
            const int R = wm * 128 + i * 16 + l15;                        \
            aF[i] = *(const half8*)((const char*)&As[buf][ks][0] +        \
                                    R * 64 + ((g ^ ((R >> 1) & 3)) << 4));\
        }                                                                 \
    } while (0)
#define READB(buf, ks, nh) do {                                           \
        _Pragma("unroll")                                                 \
        for (int jj = 0; jj < 2; jj++) {                                  \
            const int R = wn * 64 + ((nh) * 2 + jj) * 16 + l15;           \
            bF[jj] = *(const half8*)((const char*)&Bs[buf][ks][0] +       \
                                     R * 64 + ((g ^ ((R >> 1) & 3)) << 4));\
        }                                                                 \
    } while (0)
#define MFMA16(nh) do {                                                   \
        __builtin_amdgcn_s_setprio(1);                                    \
        _Pragma("unroll")                                                 \
        for (int i = 0; i < 8; i++) {                                     \
            acc[i][(nh) * 2 + 0] = __builtin_amdgcn_mfma_f32_16x16x32_f16(\
                aF[i], bF[0], acc[i][(nh) * 2 + 0], 0, 0, 0);             \
            acc[i][(nh) * 2 + 1] = __builtin_amdgcn_mfma_f32_16x16x32_f16(\
                aF[i], bF[1], acc[i][(nh) * 2 + 1], 0, 0, 0);             \
        }                                                                 \
        __builtin_amdgcn_s_setprio(0);                                    \
    } while (0)
#define FENCE_MID() do {                                                  \
        __builtin_amdgcn_s_barrier();                                     \
        asm volatile("s_waitcnt lgkmcnt(0)" ::: "memory");                \
        __builtin_amdgcn_sched_barrier(0);                                \
    } while (0)

    floatx4 acc[8][4];
#pragma unroll
    for (int i = 0; i < 8; i++)
#pragma unroll
        for (int j = 0; j < 4; j++) acc[i][j] = 0;

    const int nt = K >> 6;
    // prologue: tile0 all 4 halves + tile1 first 2 halves (12 gloads)
    STA(0, 0, 0); STB(0, 0, 0); STA(1, 0, 0); STB(1, 0, 0);
    STA(0, 1, 1); STB(0, 1, 1);

    for (int t = 0; t < nt; ++t) {
        const int buf = t & 1, nbuf = buf ^ 1;
        // tile boundary: counted drain -> tile t fully resident
        if (t == nt - 1) asm volatile("s_waitcnt vmcnt(0)" ::: "memory");
        else             asm volatile("s_waitcnt vmcnt(4)" ::: "memory");
        __builtin_amdgcn_s_barrier();
        // phase 0: quadrant (ks=0, nh=0); stage (t+1).A.k1
        READA(buf, 0); READB(buf, 0, 0);
        if (t + 1 < nt) STA(1, t + 1, nbuf);
        FENCE_MID();
        MFMA16(0);
        __builtin_amdgcn_s_barrier();
        // phase 1: quadrant (ks=0, nh=1); stage (t+1).B.k1
        READB(buf, 0, 1);
        if (t + 1 < nt) STB(1, t + 1, nbuf);
        FENCE_MID();
        MFMA16(1);
        __builtin_amdgcn_s_barrier();
        // phase 2: quadrant (ks=1, nh=0); stage (t+2).A.k0 (recycles buf)
        READA(buf, 1); READB(buf, 1, 0);
        if (t + 2 < nt) STA(0, t + 2, buf);
        FENCE_MID();
        MFMA16(0);
        __builtin_amdgcn_s_barrier();
        // phase 3: quadrant (ks=1, nh=1); stage (t+2).B.k0
        READB(buf, 1, 1);
        if (t + 2 < nt) STB(0, t + 2, buf);
        FENCE_MID();
        MFMA16(1);
        __builtin_amdgcn_s_barrier();
    }
#undef STA
#undef STB
#undef READA
#undef READB
#undef MFMA16
#undef FENCE_MID

    // epilogue: D frag mapping col = lane&15, row = (lane>>4)*4 + e
#pragma unroll
    for (int i = 0; i < 8; i++) {
#pragma unroll
        for (int e = 0; e < 4; e++) {
            const int row = m0 + wm * 128 + i * 16 + g * 4 + e;
#pragma unroll
            for (int j = 0; j < 4; j++) {
                const int col = n0 + wn * 64 + j * 16 + l15;
                Cf[(size_t)row * N + col] = acc[i][j][e];
            }
        }
    }
}

// ---------------------------------------------------------------------------
// MFMA fp16 GEMM (NT): C[M,N] = A[M,K] * B[N,K]^T, fp32 accumulate.
// Tile TM x 128, BK=32, 4 waves. 2-phase prefetch, double-buffered LDS.
// EPI: 0 = Cf store; 1 = Cf += ; 2 = Ch = swish(v); 3 = Ch = AUXh * v;
//      4 = qkv split store (fp16) with fused RoPE on q,k
// ---------------------------------------------------------------------------
template <int EPI, bool MFAST, int TM>
__global__ __launch_bounds__(256) void hgemm(const _Float16* __restrict__ A,
                                             const _Float16* __restrict__ B,
                                             float* __restrict__ Cf,
                                             _Float16* Ch,
                                             const _Float16* AUXh,
                                             _Float16* Cq,
                                             _Float16* Ck,
                                             _Float16* Cv,
                                             int M, int N, int K) {
    constexpr int WN = (TM == 128) ? 2 : 4;
    constexpr int CW = 128 / WN;
    constexpr int FN = CW / 16;
    __shared__ __align__(16) _Float16 As[2][TM * 32];
    __shared__ __align__(16) _Float16 Bs[2][128 * 32];
    const int tid = threadIdx.x;
    const int lane = tid & 63;
    const int wave = tid >> 6;
    const int wr = (TM == 128) ? (wave >> 1) : 0;
    const int wc = (TM == 128) ? (wave & 1) : wave;
    const int l15 = lane & 15, g = lane >> 4;

    const int gm = M / TM, gn = N >> 7, nwg = gm * gn;
    const int orig = blockIdx.x;
    const int q8 = nwg >> 3, r8 = nwg & 7, xcd = orig & 7, j8 = orig >> 3;
    const int wgid = (xcd < r8 ? xcd * (q8 + 1) : r8 * (q8 + 1) + (xcd - r8) * q8) + j8;
    const int bm = MFAST ? (wgid % gm) : (wgid / gn);
    const int bn = MFAST ? (wgid / gm) : (wgid % gn);
    const int m0 = bm * TM, n0 = bn * 128;

    const int offA0 = wave * (TM * 16) + lane * 16;
    const int offA1 = offA0 + 1024;
    const int rA0 = offA0 >> 6, kA0 = offA0 & 63;
    const int rA1 = offA1 >> 6, kA1 = offA1 & 63;
    const int offB0 = wave * 2048 + lane * 16;
    const int offB1 = offB0 + 1024;
    const int rB0 = offB0 >> 6, kB0 = offB0 & 63;
    const int rB1 = offB1 >> 6, kB1 = offB1 & 63;
    const char* gA0 = (const char*)(A + (size_t)(m0 + rA0) * K) + kA0;
    const char* gA1 = (const char*)(A + (size_t)(m0 + rA1) * K) + kA1;
    const char* gB0 = (const char*)(B + (size_t)(n0 + rB0) * K) + kB0;
    const char* gB1 = (const char*)(B + (size_t)(n0 + rB1) * K) + kB1;

#define STAGE(buf)                                                     \
    do {                                                               \
        gload16(gA0, (char*)As[buf] + offA0);                          \
        if constexpr (TM == 128) gload16(gA1, (char*)As[buf] + offA1); \
        gload16(gB0, (char*)Bs[buf] + offB0);                          \
        gload16(gB1, (char*)Bs[buf] + offB1);                          \
        gA0 += 64; gA1 += 64; gB0 += 64; gB1 += 64;                    \
    } while (0)

    floatx4 acc[4][FN];
#pragma unroll
    for (int i = 0; i < 4; i++)
#pragma unroll
        for (int j = 0; j < FN; j++) acc[i][j] = 0;

    STAGE(0);
    __syncthreads();
    int cur = 0;
    for (int kk = 0; kk < K; kk += 32) {
        if (kk + 32 < K) STAGE(cur ^ 1);
        half8 aF[4], bF[FN];
#pragma unroll
        for (int i = 0; i < 4; i++)
            aF[i] = *(const half8*)&As[cur][(wr * 64 + i * 16 + l15) * 32 + g * 8];
#pragma unroll
        for (int j = 0; j < FN; j++)
            bF[j] = *(const half8*)&Bs[cur][(wc * CW + j * 16 + l15) * 32 + g * 8];
#pragma unroll
        for (int i = 0; i < 4; i++)
#pragma unroll
            for (int j = 0; j < FN; j++)
                acc[i][j] = __builtin_amdgcn_mfma_f32_16x16x32_f16(aF[i], bF[j], acc[i][j], 0, 0, 0);
        __syncthreads();
        cur ^= 1;
    }
#undef STAGE

    const int rb = m0 + wr * 64 + g * 4;
    const int cb = n0 + wc * CW + l15;
    if (EPI == 4) {
        const int sel = n0 >> 10;
        _Float16* Cx = sel == 0 ? Cq : (sel == 1 ? Ck : Cv);
        const int cb0 = cb - sel * 1024;
#pragma unroll
        for (int i = 0; i < 4; i++) {
#pragma unroll
            for (int e = 0; e < 4; e++) {
                const int row = rb + i * 16 + e;
                const int pos = row & (S_SZ - 1);
#pragma unroll
                for (int j = 0; j < FN; j++) {
                    float v = acc[i][j][e];
                    const int col = cb0 + j * 16;
                    if (sel < 2) {
                        const float pp = __shfl_xor(v, 1, 64);
                        const int pi = (col & 63) >> 1;
                        const float invf = exp2f((float)pi * -0.41524101186f);
                        float sn, cs;
                        sincosf((float)pos * invf, &sn, &cs);
                        v = (col & 1) ? (pp * sn + v * cs) : (v * cs - pp * sn);
                    }
                    Cx[(size_t)row * 1024 + col] = (_Float16)v;
                }
            }
        }
        return;
    }
#pragma unroll
    for (int i = 0; i < 4; i++) {
#pragma unroll
        for (int e = 0; e < 4; e++) {
            const int row = rb + i * 16 + e;
#pragma unroll
            for (int j = 0; j < FN; j++) {
                const float v = acc[i][j][e];
                const int col = cb + j * 16;
                if (EPI == 0) {
                    Cf[(size_t)row * N + col] = v;
                } else if (EPI == 1) {
                    Cf[(size_t)row * N + col] += v;
                } else if (EPI == 2) {
                    Ch[(size_t)row * N + col] =
                        (_Float16)(v / (1.0f + __expf(-v)));
                } else if (EPI == 3) {
                    const size_t idx = (size_t)row * N + col;
                    Ch[idx] = (_Float16)((float)AUXh[idx] * v);
                }
            }
        }
    }
}

// ---------------------------------------------------------------------------
// Fused SwiGLU GEMM: out[M,F] = swish(A@B1^T) * (A@B3^T), fp16 out.
// ---------------------------------------------------------------------------
__global__ __launch_bounds__(256) void hgemm_ff(const _Float16* __restrict__ A,
                                                const _Float16* __restrict__ B1,
                                                const _Float16* __restrict__ B3,
                                                _Float16* __restrict__ Ch,
                                                int M, int N, int K) {
    __shared__ __align__(16) _Float16 As[2][64 * 32];
    __shared__ __align__(16) _Float16 Bs1[2][128 * 32];
    __shared__ __align__(16) _Float16 Bs3[2][128 * 32];
    const int tid = threadIdx.x;
    const int lane = tid & 63;
    const int wave = tid >> 6;
    const int l15 = lane & 15, g = lane >> 4;

    const int gm = M >> 6, gn = N >> 7, nwg = gm * gn;
    const int orig = blockIdx.x;
    const int q8 = nwg >> 3, r8 = nwg & 7, xcd = orig & 7, j8 = orig >> 3;
    const int wgid = (xcd < r8 ? xcd * (q8 + 1) : r8 * (q8 + 1) + (xcd - r8) * q8) + j8;
    const int bm = wgid % gm, bn = wgid / gm;
    const int m0 = bm * 64, n0 = bn * 128;

    const int offA = wave * 1024 + lane * 16;
    const int rA = offA >> 6, kA = offA & 63;
    const int offB0 = wave * 2048 + lane * 16;
    const int offB1 = offB0 + 1024;
    const int rB0 = offB0 >> 6, kB0 = offB0 & 63;
    const int rB1 = offB1 >> 6, kB1 = offB1 & 63;
    const char* gA  = (const char*)(A  + (size_t)(m0 + rA) * K) + kA;
    const char* gB10 = (const char*)(B1 + (size_t)(n0 + rB0) * K) + kB0;
    const char* gB11 = (const char*)(B1 + (size_t)(n0 + rB1) * K) + kB1;
    const char* gB30 = (const char*)(B3 + (size_t)(n0 + rB0) * K) + kB0;
    const char* gB31 = (const char*)(B3 + (size_t)(n0 + rB1) * K) + kB1;

#define STAGEF(buf)                                   \
    do {                                              \
        gload16(gA,   (char*)As[buf]  + offA);        \
        gload16(gB10, (char*)Bs1[buf] + offB0);       \
        gload16(gB11, (char*)Bs1[buf] + offB1);       \
        gload16(gB30, (char*)Bs3[buf] + offB0);       \
        gload16(gB31, (char*)Bs3[buf] + offB1);       \
        gA += 64; gB10 += 64; gB11 += 64;             \
        gB30 += 64; gB31 += 64;                       \
    } while (0)

    floatx4 acc1[4][2], acc3[4][2];
#pragma unroll
    for (int i = 0; i < 4; i++)
#pragma unroll
        for (int j = 0; j < 2; j++) { acc1[i][j] = 0; acc3[i][j] = 0; }

    STAGEF(0);
    __syncthreads();
    int cur = 0;
    for (int kk = 0; kk < K; kk += 32) {
        if (kk + 32 < K) STAGEF(cur ^ 1);
        half8 aF[4], b1F[2], b3F[2];
#pragma unroll
        for (int i = 0; i < 4; i++)
            aF[i] = *(const half8*)&As[cur][(i * 16 + l15) * 32 + g * 8];
#pragma unroll
        for (int j = 0; j < 2; j++) {
            b1F[j] = *(const half8*)&Bs1[cur][(wave * 32 + j * 16 + l15) * 32 + g * 8];
            b3F[j] = *(const half8*)&Bs3[cur][(wave * 32 + j * 16 + l15) * 32 + g * 8];
        }
#pragma unroll
        for (int i = 0; i < 4; i++)
#pragma unroll
            for (int j = 0; j < 2; j++) {
                acc1[i][j] = __builtin_amdgcn_mfma_f32_16x16x32_f16(aF[i], b1F[j], acc1[i][j], 0, 0, 0);
                acc3[i][j] = __builtin_amdgcn_mfma_f32_16x16x32_f16(aF[i], b3F[j], acc3[i][j], 0, 0, 0);
            }
        __syncthreads();
        cur ^= 1;
    }
#undef STAGEF

    const int cb = n0 + wave * 32 + l15;
#pragma unroll
    for (int i = 0; i < 4; i++) {
#pragma unroll
        for (int e = 0; e < 4; e++) {
            const int row = m0 + i * 16 + g * 4 + e;
#pragma unroll
            for (int j = 0; j < 2; j++) {
                const float v1 = acc1[i][j][e];
                const float v3 = acc3[i][j][e];
                const float sw = v1 / (1.0f + __expf(-v1));
                Ch[(size_t)row * N + cb + j * 16] = (_Float16)(sw * v3);
            }
        }
    }
}

// ---------------------------------------------------------------------------
// Per-head V transpose: vh[b,s,h*64+d] -> vt[(b*16+h)*64+d][s]
// ---------------------------------------------------------------------------
__global__ __launch_bounds__(256) void vtrans(const _Float16* __restrict__ vh,
                                              _Float16* __restrict__ vt) {
    __shared__ __align__(16) _Float16 Ls[64][80];
    const int t = threadIdx.x;
    const int s0 = blockIdx.x * 64;
    const int bh = blockIdx.y;
    const int b = bh >> 4, h = bh & 15;
#pragma unroll
    for (int p = 0; p < 2; ++p) {
        const int sl = p * 32 + (t >> 3);
        const int d = (t & 7) * 8;
        *(half8*)&Ls[sl][d] =
            *(const half8*)&vh[((size_t)b * S_SZ + s0 + sl) * D_SZ + h * 64 + d];
    }
    __syncthreads();
#pragma unroll
    for (int p = 0; p < 2; ++p) {
        const int d = p * 32 + (t >> 3);
        const int sc = (t & 7) * 8;
        half8 v;
#pragma unroll
        for (int j = 0; j < 8; ++j) v[j] = Ls[sc + j][d];
        *(half8*)&vt[((size_t)bh * 64 + d) * S_SZ + s0 + sc] = v;
    }
}

// ---------------------------------------------------------------------------
// MFMA flash attention (causal), fp16 in/out, fp32 softmax state.
// ---------------------------------------------------------------------------
__global__ __launch_bounds__(256) void attn_mfma(const _Float16* __restrict__ qh,
                                                 const _Float16* __restrict__ kh,
                                                 const _Float16* __restrict__ vt,
                                                 _Float16* __restrict__ o) {
    __shared__ __align__(16) _Float16 Ks[2][64 * 64];
    __shared__ __align__(16) _Float16 Vs[2][64 * 64];
    __shared__ __align__(16) _Float16 Ps[4][16][88];
    const int tid = threadIdx.x;
    const int lane = tid & 63, wave = tid >> 6;
    const int l15 = lane & 15, g = lane >> 4;
    const int bx = blockIdx.x;
    const int bh = blockIdx.y;
    const int h = bh & 15;
    const size_t tokb = (size_t)(bh >> 4) * S_SZ;

    const int qt0 = bx, qt1 = 15 - bx;
    const int qb0 = qt0 * 64, qb1 = qt1 * 64;
    const int ktmax = qt1;

    const int qrow = l15 * 4 + wave;
    half8 qA0[2], qA1[2];
#pragma unroll
    for (int kk = 0; kk < 2; ++kk) {
        qA0[kk] = *(const half8*)&qh[(tokb + qb0 + qrow) * D_SZ + h * 64 + kk * 32 + g * 8];
        qA1[kk] = *(const half8*)&qh[(tokb + qb1 + qrow) * D_SZ + h * 64 + kk * 32 + g * 8];
    }

    floatx4 accO0[4], accO1[4];
#pragma unroll
    for (int s = 0; s < 4; s++) { accO0[s] = 0; accO1[s] = 0; }
    float m0_[4] = {NEG_INF, NEG_INF, NEG_INF, NEG_INF};
    float l0_[4] = {0.0f, 0.0f, 0.0f, 0.0f};
    float m1_[4] = {NEG_INF, NEG_INF, NEG_INF, NEG_INF};
    float l1_[4] = {0.0f, 0.0f, 0.0f, 0.0f};

    const char* KbB = (const char*)(kh + tokb * D_SZ + h * 64);
    const char* VbB = (const char*)(vt + (size_t)bh * 64 * S_SZ);
    const int so0 = wave * 2048 + lane * 16;
    const int so1 = so0 + 1024;
    const int r0 = so0 >> 7, c0 = (so0 >> 4) & 7;
    const int r1 = so1 >> 7, c1 = (so1 >> 4) & 7;
    const int gc0 = ((c0 ^ (r0 & 7)) << 4);
    const int gc1 = ((c1 ^ (r1 & 7)) << 4);

#define STAGEKV(buf, kt)                                                   \
    do {                                                                   \
        const size_t kvr = (size_t)(kt) * 64;                              \
        gload16(KbB + (kvr + r0) * 2048 + gc0, (char*)Ks[buf] + so0);      \
        gload16(KbB + (kvr + r1) * 2048 + gc1, (char*)Ks[buf] + so1);      \
        gload16(VbB + r0 * 2048 + kvr * 2 + gc0, (char*)Vs[buf] + so0);    \
        gload16(VbB + r1 * 2048 + kvr * 2 + gc1, (char*)Vs[buf] + so1);    \
    } while (0)

#define LDSW(arr, rr, cc) \
    (*(const half8*)&(arr)[(rr) * 64 + ((((cc) ^ ((rr) & 7))) << 3)])

    auto computeTile = [&](const half8* qA, floatx4* accO, float* m_, float* l_,
                           int qbase, int kt, bool diag, int buf) {
        const int kv0 = kt * 64;
        floatx4 accS[4];
        __builtin_amdgcn_s_setprio(1);
#pragma unroll
        for (int sub = 0; sub < 4; ++sub) {
            accS[sub] = 0;
#pragma unroll
            for (int kk = 0; kk < 2; ++kk) {
                half8 kB = LDSW(Ks[buf], sub * 16 + l15, kk * 4 + g);
                accS[sub] = __builtin_amdgcn_mfma_f32_16x16x32_f16(qA[kk], kB, accS[sub], 0, 0, 0);
            }
        }
        __builtin_amdgcn_s_setprio(0);
        float sv[4][4];
        float mx[4] = {NEG_INF, NEG_INF, NEG_INF, NEG_INF};
#pragma unroll
        for (int sub = 0; sub < 4; ++sub)
#pragma unroll
            for (int e = 0; e < 4; ++e) {
                float s = accS[sub][e] * 0.125f;
                if (diag && (kv0 + sub * 16 + l15 > qbase + (g * 4 + e) * 4 + wave))
                    s = NEG_INF;
                sv[sub][e] = s;
                mx[e] = fmaxf(mx[e], s);
            }
#pragma unroll
        for (int msk = 1; msk <= 8; msk <<= 1)
#pragma unroll
            for (int e = 0; e < 4; ++e)
                mx[e] = fmaxf(mx[e], __shfl_xor(mx[e], msk, 64));
        float sf[4];
#pragma unroll
        for (int e = 0; e < 4; ++e) {
            const float mn = fmaxf(m_[e], mx[e]);
            sf[e] = __expf(m_[e] - mn);
            m_[e] = mn;
        }
        float rs[4] = {0.0f, 0.0f, 0.0f, 0.0f};
#pragma unroll
        for (int sub = 0; sub < 4; ++sub)
#pragma unroll
            for (int e = 0; e < 4; ++e) {
                const float p = __expf(sv[sub][e] - m_[e]);
                sv[sub][e] = p;
                rs[e] += p;
            }
#pragma unroll
        for (int msk = 1; msk <= 8; msk <<= 1)
#pragma unroll
            for (int e = 0; e < 4; ++e)
                rs[e] += __shfl_xor(rs[e], msk, 64);
#pragma unroll
        for (int e = 0; e < 4; ++e) l_[e] = l_[e] * sf[e] + rs[e];
#pragma unroll
        for (int sub = 0; sub < 4; ++sub)
#pragma unroll
            for (int e = 0; e < 4; ++e) accO[sub][e] *= sf[e];
#pragma unroll
        for (int sub = 0; sub < 4; ++sub)
#pragma unroll
            for (int e = 0; e < 4; ++e)
                Ps[wave][g * 4 + e][sub * 16 + l15] = (_Float16)sv[sub][e];
        half8 aP[2];
        aP[0] = *(const half8*)&Ps[wave][l15][g * 8];
        aP[1] = *(const half8*)&Ps[wave][l15][32 + g * 8];
        __builtin_amdgcn_s_setprio(1);
#pragma unroll
        for (int sub = 0; sub < 4; ++sub)
#pragma unroll
            for (int kk = 0; kk < 2; ++kk) {
                half8 vB = LDSW(Vs[buf], sub * 16 + l15, kk * 4 + g);
                accO[sub] = __builtin_amdgcn_mfma_f32_16x16x32_f16(aP[kk], vB, accO[sub], 0, 0, 0);
            }
        __builtin_amdgcn_s_setprio(0);
    };

    STAGEKV(0, 0);
    __syncthreads();
    int cur = 0;
    for (int kt = 0; kt <= ktmax; ++kt) {
        if (kt < ktmax) STAGEKV(cur ^ 1, kt + 1);
        computeTile(qA1, accO1, m1_, l1_, qb1, kt, kt == qt1, cur);
        if (kt <= qt0)
            computeTile(qA0, accO0, m0_, l0_, qb0, kt, kt == qt0, cur);
        __syncthreads();
        cur ^= 1;
    }
#undef STAGEKV
#undef LDSW

#pragma unroll
    for (int sub = 0; sub < 4; ++sub)
#pragma unroll
        for (int e = 0; e < 4; ++e) {
            const int rr = (g * 4 + e) * 4 + wave;
            o[(tokb + qb1 + rr) * D_SZ + h * 64 + sub * 16 + l15] =
                (_Float16)(accO1[sub][e] / l1_[e]);
            o[(tokb + qb0 + rr) * D_SZ + h * 64 + sub * 16 + l15] =
                (_Float16)(accO0[sub][e] / l0_[e]);
        }
}

// ---------------------------------------------------------------------------
// Host-side launch
// ---------------------------------------------------------------------------
extern "C" void kernel_launch(void* const* d_in, const int* in_sizes, int n_in,
                              void* d_out, int out_size, void* d_ws, size_t ws_size,
                              hipStream_t stream) {
    const int*   token_ids  = (const int*)d_in[0];
    const float* tok_emb    = (const float*)d_in[1];
    const float* lm_head_w  = (const float*)d_in[2];
    const float* ln_final_w = (const float*)d_in[3];
    const float* q_w        = (const float*)d_in[4];
    const float* k_w        = (const float*)d_in[5];
    const float* v_w        = (const float*)d_in[6];
    const float* o_w        = (const float*)d_in[7];
    const float* ln1_w      = (const float*)d_in[8];
    const float* ln2_w      = (const float*)d_in[9];
    const float* w1         = (const float*)d_in[10];
    const float* w2         = (const float*)d_in[11];
    const float* w3         = (const float*)d_in[12];
    float* out = (float*)d_out;

    char* W = (char*)d_ws;
    const size_t MB = 1u << 20;
    float*    x    = (float*)(W + 0);           // 8 MB
    _Float16* h    = (_Float16*)(W + 8 * MB);   // 4 MB
    _Float16* ao   = (_Float16*)(W + 12 * MB);  // 4 MB
    _Float16* wq   = (_Float16*)(W + 16 * MB);  // 8 MB: q/k/v/o contiguous
    _Float16* wo   = wq + 3 * (1u << 20);
    _Float16* ww1  = (_Float16*)(W + 24 * MB);  // 24 MB: w1/w3/w2 contiguous
    _Float16* ww3  = ww1 + (size_t)F_SZ * D_SZ;
    _Float16* ww2  = ww1 + 2 * (size_t)F_SZ * D_SZ;
    _Float16* qh   = (_Float16*)(W + 48 * MB);  // 4 MB
    _Float16* kh   = (_Float16*)(W + 52 * MB);  // 4 MB
    _Float16* vh   = (_Float16*)(W + 56 * MB);  // 4 MB
    _Float16* vt   = (_Float16*)(W + 60 * MB);  // 4 MB
    _Float16* ff1h = (_Float16*)(W + 64 * MB);  // 16 MB -> 80 MB
    _Float16* whead = (_Float16*)(W + 24 * MB); // 62.5 MB, overlaps dead ww*

    embed_kernel<<<NTOK, 256, 0, stream>>>(token_ids, tok_emb, x);

    const int nDD8 = D_SZ * D_SZ / 8;     // 131072
    const int nFD8 = F_SZ * D_SZ / 8;     // 524288
    const int nCNV = 4 * nDD8 + 3 * nFD8; // 2097152
    const dim3 gQKV(3 * D_SZ / 128 * (NTOK / 128));   // 384
    const dim3 gD64(D_SZ / 128 * (NTOK / 64));        // 256 (TM=64)
    const dim3 gFF(F_SZ / 128 * (NTOK / 64));         // 1024 (fused swiglu)
    const dim3 gATT(S_SZ / 128, B_SZ * H_SZ);         // (8,32), paired tiles
    const dim3 gVT(S_SZ / 64, B_SZ * H_SZ);

    for (int l = 0; l < L_SZ; l++) {
        const size_t oDD = (size_t)l * D_SZ * D_SZ;
        const size_t oFD = (size_t)l * F_SZ * D_SZ;
        rmsnorm_kernel<<<NTOK, 256, 0, stream>>>(x, ln1_w + (size_t)l * D_SZ, h);
        f2h7<<<nCNV / 256, 256, 0, stream>>>(q_w + oDD, k_w + oDD, v_w + oDD,
                                             o_w + oDD, w1 + oFD, w3 + oFD,
                                             w2 + oFD, wq, nDD8, nFD8);
        hgemm<4, true, 128><<<gQKV, 256, 0, stream>>>(h, wq, nullptr, nullptr, nullptr,
                                                      qh, kh, vh, NTOK, 3 * D_SZ, D_SZ);
        vtrans<<<gVT, 256, 0, stream>>>(vh, vt);
        attn_mfma<<<gATT, 256, 0, stream>>>(qh, kh, vt, ao);
        hgemm<1, false, 64><<<gD64, 256, 0, stream>>>(ao, wo, x, nullptr, nullptr,
                                                      nullptr, nullptr, nullptr, NTOK, D_SZ, D_SZ);
        rmsnorm_kernel<<<NTOK, 256, 0, stream>>>(x, ln2_w + (size_t)l * D_SZ, h);
        hgemm_ff<<<gFF, 256, 0, stream>>>(h, ww1, ww3, ff1h, NTOK, F_SZ, D_SZ);
        hgemm<1, false, 64><<<gD64, 256, 0, stream>>>(ff1h, ww2, x, nullptr, nullptr,
                                                      nullptr, nullptr, nullptr, NTOK, D_SZ, F_SZ);
    }
    rmsnorm_kernel<<<NTOK, 256, 0, stream>>>(x, ln_final_w, h);
    const int nVD8 = V_SZ * D_SZ / 8;
    f2h<<<(nVD8 + 255) / 256, 256, 0, stream>>>(lm_head_w, whead, nVD8);
    const dim3 gOUT(V_SZ / 256 * (NTOK / 256));       // 1000 (256^2, 8-phase)
    hgemm8p<true><<<gOUT, 512, 0, stream>>>(h, whead, out, NTOK, V_SZ, D_SZ);
}

// Round 11
// 1181.697 us; speedup vs baseline: 1.0278x; 1.0278x over previous
//
#include <hip/hip_runtime.h>
#include <math.h>

// Problem constants (from reference)
#define V_SZ 32000
#define D_SZ 1024
#define H_SZ 16
#define L_SZ 4
#define F_SZ 4096
#define S_SZ 1024
#define B_SZ 2
#define DK 64              // D/H
#define NTOK (B_SZ * S_SZ) // 2048
#define NEG_INF -3.0e38f

typedef _Float16 half8 __attribute__((ext_vector_type(8)));
typedef _Float16 half4 __attribute__((ext_vector_type(4)));
typedef float floatx4 __attribute__((ext_vector_type(4)));

// async global->LDS, 16B per lane; lds dest is wave-uniform base + lane*16.
__device__ __forceinline__ void gload16(const void* g, void* l) {
    __builtin_amdgcn_global_load_lds(
        (const __attribute__((address_space(1))) unsigned int*)g,
        (__attribute__((address_space(3))) unsigned int*)l, 16, 0, 0);
}

// ---------------------------------------------------------------------------
// prep1: fused rmsnorm (blocks [0,NTOK)) + 7-matrix f2h (rest). Both parts
// are block-uniform branches; they share one launch/sync point.
// ---------------------------------------------------------------------------
__global__ __launch_bounds__(256) void prep1(const float* __restrict__ x,
                                             const float* __restrict__ lnw,
                                             _Float16* __restrict__ hout,
                                             const float* __restrict__ sq,
                                             const float* __restrict__ sk,
                                             const float* __restrict__ sv,
                                             const float* __restrict__ so,
                                             const float* __restrict__ s1,
                                             const float* __restrict__ s3,
                                             const float* __restrict__ s2,
                                             _Float16* __restrict__ d,
                                             int nDD8, int nFD8) {
    const int tid = threadIdx.x;
    if (blockIdx.x < NTOK) {
        const int row = blockIdx.x;
        const float4 v = ((const float4*)(x + (size_t)row * D_SZ))[tid];
        float ss = v.x * v.x + v.y * v.y + v.z * v.z + v.w * v.w;
#pragma unroll
        for (int off = 32; off > 0; off >>= 1) ss += __shfl_down(ss, off, 64);
        __shared__ float red[4];
        if ((tid & 63) == 0) red[tid >> 6] = ss;
        __syncthreads();
        const float tot = red[0] + red[1] + red[2] + red[3];
        const float inv = 1.0f / (sqrtf(tot * (1.0f / (float)D_SZ)) + 1e-5f);
        const float4 wv = ((const float4*)lnw)[tid];
        half4 o = {(_Float16)(v.x * inv * wv.x), (_Float16)(v.y * inv * wv.y),
                   (_Float16)(v.z * inv * wv.z), (_Float16)(v.w * inv * wv.w)};
        ((half4*)(hout + (size_t)row * D_SZ))[tid] = o;
        return;
    }
    const int i = (blockIdx.x - NTOK) * 256 + tid;
    const float* s;
    int off;
    if (i < 4 * nDD8) {
        const int sel = i / nDD8;
        off = i - sel * nDD8;
        s = sel == 0 ? sq : (sel == 1 ? sk : (sel == 2 ? sv : so));
    } else {
        const int j = i - 4 * nDD8;
        const int sel = j / nFD8;
        off = j - sel * nFD8;
        s = sel == 0 ? s1 : (sel == 1 ? s3 : s2);
    }
    const float4 a = ((const float4*)s)[2 * off];
    const float4 b = ((const float4*)s)[2 * off + 1];
    half8 hv = {(_Float16)a.x, (_Float16)a.y, (_Float16)a.z, (_Float16)a.w,
                (_Float16)b.x, (_Float16)b.y, (_Float16)b.z, (_Float16)b.w};
    ((half8*)d)[i] = hv;
}

// ---------------------------------------------------------------------------
// prep2: fused final rmsnorm (blocks [0,NTOK)) + lm_head f2h (rest; n8 is
// exactly (grid-NTOK)*256 so no bounds check).
// ---------------------------------------------------------------------------
__global__ __launch_bounds__(256) void prep2(const float* __restrict__ x,
                                             const float* __restrict__ lnw,
                                             _Float16* __restrict__ hout,
                                             const float* __restrict__ win,
                                             _Float16* __restrict__ wout) {
    const int tid = threadIdx.x;
    if (blockIdx.x < NTOK) {
        const int row = blockIdx.x;
        const float4 v = ((const float4*)(x + (size_t)row * D_SZ))[tid];
        float ss = v.x * v.x + v.y * v.y + v.z * v.z + v.w * v.w;
#pragma unroll
        for (int off = 32; off > 0; off >>= 1) ss += __shfl_down(ss, off, 64);
        __shared__ float red[4];
        if ((tid & 63) == 0) red[tid >> 6] = ss;
        __syncthreads();
        const float tot = red[0] + red[1] + red[2] + red[3];
        const float inv = 1.0f / (sqrtf(tot * (1.0f / (float)D_SZ)) + 1e-5f);
        const float4 wv = ((const float4*)lnw)[tid];
        half4 o = {(_Float16)(v.x * inv * wv.x), (_Float16)(v.y * inv * wv.y),
                   (_Float16)(v.z * inv * wv.z), (_Float16)(v.w * inv * wv.w)};
        ((half4*)(hout + (size_t)row * D_SZ))[tid] = o;
        return;
    }
    const int i = (blockIdx.x - NTOK) * 256 + tid;
    const float4 a = ((const float4*)win)[2 * i];
    const float4 b = ((const float4*)win)[2 * i + 1];
    half8 hv = {(_Float16)a.x, (_Float16)a.y, (_Float16)a.z, (_Float16)a.w,
                (_Float16)b.x, (_Float16)b.y, (_Float16)b.z, (_Float16)b.w};
    ((half8*)wout)[i] = hv;
}

// ---------------------------------------------------------------------------
// Embedding gather (fp32)
// ---------------------------------------------------------------------------
__global__ __launch_bounds__(256) void embed_kernel(const int* __restrict__ ids,
                                                    const float* __restrict__ emb,
                                                    float* __restrict__ x) {
    const int row = blockIdx.x;
    const int id = ids[row];
    const float4* src = (const float4*)(emb + (size_t)id * D_SZ);
    float4* dst = (float4*)(x + (size_t)row * D_SZ);
    dst[threadIdx.x] = src[threadIdx.x];
}

// ---------------------------------------------------------------------------
// RMSNorm: fp32 in, fp16 out (standalone, used for ln2)
// ---------------------------------------------------------------------------
__global__ __launch_bounds__(256) void rmsnorm_kernel(const float* __restrict__ x,
                                                      const float* __restrict__ w,
                                                      _Float16* __restrict__ out) {
    const int row = blockIdx.x;
    const int tid = threadIdx.x;
    const float4 v = ((const float4*)(x + (size_t)row * D_SZ))[tid];
    float ss = v.x * v.x + v.y * v.y + v.z * v.z + v.w * v.w;
#pragma unroll
    for (int off = 32; off > 0; off >>= 1) ss += __shfl_down(ss, off, 64);
    __shared__ float red[4];
    if ((tid & 63) == 0) red[tid >> 6] = ss;
    __syncthreads();
    const float tot = red[0] + red[1] + red[2] + red[3];
    const float inv = 1.0f / (sqrtf(tot * (1.0f / (float)D_SZ)) + 1e-5f);
    const float4 wv = ((const float4*)w)[tid];
    half4 o = {(_Float16)(v.x * inv * wv.x), (_Float16)(v.y * inv * wv.y),
               (_Float16)(v.z * inv * wv.z), (_Float16)(v.w * inv * wv.w)};
    ((half4*)(out + (size_t)row * D_SZ))[tid] = o;
}

// ---------------------------------------------------------------------------
// 8-phase deep-pipelined 256x256 MFMA fp16 GEMM (NT). Counted vmcnt(4) per
// tile boundary; XOR swizzle chunk ^= (row>>1)&3 (0-conflict, verified r10).
// Kept for lm_head (marginally best, conflict-free). Schedule frozen.
// ---------------------------------------------------------------------------
template <bool MFAST>
__global__ __launch_bounds__(512) void hgemm8p(const _Float16* __restrict__ A,
                                               const _Float16* __restrict__ B,
                                               float* __restrict__ Cf,
                                               int M, int N, int K) {
    __shared__ __align__(16) _Float16 As[2][2][256 * 32];
    __shared__ __align__(16) _Float16 Bs[2][2][256 * 32];
    const int tid = threadIdx.x;
    const int lane = tid & 63, wave = tid >> 6;
    const int wm = wave >> 2, wn = wave & 3;
    const int l15 = lane & 15, g = lane >> 4;

    const int gm = M >> 8, gn = N >> 8, nwg = gm * gn;
    const int orig = blockIdx.x;
    const int q8 = nwg >> 3, r8 = nwg & 7, xcd = orig & 7, j8 = orig >> 3;
    const int wgid = (xcd < r8 ? xcd * (q8 + 1) : r8 * (q8 + 1) + (xcd - r8) * q8) + j8;
    const int bm = MFAST ? (wgid % gm) : (wgid / gn);
    const int bn = MFAST ? (wgid / gm) : (wgid % gn);
    const int m0 = bm << 8, n0 = bn << 8;

    const int rowS = tid >> 2;
    const int srcC = ((tid & 3) ^ ((rowS >> 1) & 3)) << 4;
    const size_t Kb = (size_t)K * 2;
    const char* gA = (const char*)A + (size_t)(m0 + rowS) * Kb + srcC;
    const char* gB = (const char*)B + (size_t)(n0 + rowS) * Kb + srcC;
    const size_t g128 = 128 * Kb;

#define STA(ks, t, buf) do {                                              \
        const char* _s = gA + (size_t)(t) * 128 + (ks) * 64;              \
        char* _d = (char*)&As[buf][ks][0];                                \
        gload16(_s, _d + tid * 16);                                       \
        gload16(_s + g128, _d + 8192 + tid * 16);                         \
    } while (0)
#define STB(ks, t, buf) do {                                              \
        const char* _s = gB + (size_t)(t) * 128 + (ks) * 64;              \
        char* _d = (char*)&Bs[buf][ks][0];                                \
        gload16(_s, _d + tid * 16);                                       \
        gload16(_s + g128, _d + 8192 + tid * 16);                         \
    } while (0)

    half8 aF[8], bF[2];
#define READA(buf, ks) do {                                               \
        _Pragma("unroll")                                                 \
        for (int i = 0; i < 8; i++) {                                     \
            const int R = wm * 128 + i * 16 + l15;                        \
            aF[i] = *(const half8*)((const char*)&As[buf][ks][0] +        \
                                    R * 64 + ((g ^ ((R >> 1) & 3)) << 4));\
        }                                                                 \
    } while (0)
#define READB(buf, ks, nh) do {                                           \
        _Pragma("unroll")                                                 \
        for (int jj = 0; jj < 2; jj++) {                                  \
            const int R = wn * 64 + ((nh) * 2 + jj) * 16 + l15;           \
            bF[jj] = *(const half8*)((const char*)&Bs[buf][ks][0] +       \
                                     R * 64 + ((g ^ ((R >> 1) & 3)) << 4));\
        }                                                                 \
    } while (0)
#define MFMA16(nh) do {                                                   \
        __builtin_amdgcn_s_setprio(1);                                    \
        _Pragma("unroll")                                                 \
        for (int i = 0; i < 8; i++) {                                     \
            acc[i][(nh) * 2 + 0] = __builtin_amdgcn_mfma_f32_16x16x32_f16(\
                aF[i], bF[0], acc[i][(nh) * 2 + 0], 0, 0, 0);             \
            acc[i][(nh) * 2 + 1] = __builtin_amdgcn_mfma_f32_16x16x32_f16(\
                aF[i], bF[1], acc[i][(nh) * 2 + 1], 0, 0, 0);             \
        }                                                                 \
        __builtin_amdgcn_s_setprio(0);                                    \
    } while (0)
#define FENCE_MID() do {                                                  \
        __builtin_amdgcn_s_barrier();                                     \
        asm volatile("s_waitcnt lgkmcnt(0)" ::: "memory");                \
        __builtin_amdgcn_sched_barrier(0);                                \
    } while (0)

    floatx4 acc[8][4];
#pragma unroll
    for (int i = 0; i < 8; i++)
#pragma unroll
        for (int j = 0; j < 4; j++) acc[i][j] = 0;

    const int nt = K >> 6;
    STA(0, 0, 0); STB(0, 0, 0); STA(1, 0, 0); STB(1, 0, 0);
    STA(0, 1, 1); STB(0, 1, 1);

    for (int t = 0; t < nt; ++t) {
        const int buf = t & 1, nbuf = buf ^ 1;
        if (t == nt - 1) asm volatile("s_waitcnt vmcnt(0)" ::: "memory");
        else             asm volatile("s_waitcnt vmcnt(4)" ::: "memory");
        __builtin_amdgcn_s_barrier();
        READA(buf, 0); READB(buf, 0, 0);
        if (t + 1 < nt) STA(1, t + 1, nbuf);
        FENCE_MID();
        MFMA16(0);
        __builtin_amdgcn_s_barrier();
        READB(buf, 0, 1);
        if (t + 1 < nt) STB(1, t + 1, nbuf);
        FENCE_MID();
        MFMA16(1);
        __builtin_amdgcn_s_barrier();
        READA(buf, 1); READB(buf, 1, 0);
        if (t + 2 < nt) STA(0, t + 2, buf);
        FENCE_MID();
        MFMA16(0);
        __builtin_amdgcn_s_barrier();
        READB(buf, 1, 1);
        if (t + 2 < nt) STB(0, t + 2, buf);
        FENCE_MID();
        MFMA16(1);
        __builtin_amdgcn_s_barrier();
    }
#undef STA
#undef STB
#undef READA
#undef READB
#undef MFMA16
#undef FENCE_MID

#pragma unroll
    for (int i = 0; i < 8; i++) {
#pragma unroll
        for (int e = 0; e < 4; e++) {
            const int row = m0 + wm * 128 + i * 16 + g * 4 + e;
#pragma unroll
            for (int j = 0; j < 4; j++) {
                const int col = n0 + wn * 64 + j * 16 + l15;
                Cf[(size_t)row * N + col] = acc[i][j][e];
            }
        }
    }
}

// ---------------------------------------------------------------------------
// MFMA fp16 GEMM (NT): C[M,N] = A[M,K] * B[N,K]^T, fp32 accumulate.
// Tile TM x 128, BK=32, 4 waves. 2-phase prefetch, double-buffered LDS.
// EPI: 0 = Cf store; 1 = Cf += ; 2 = Ch = swish(v); 3 = Ch = AUXh * v;
//      4 = qkv split store (fp16) with fused RoPE on q,k
// ---------------------------------------------------------------------------
template <int EPI, bool MFAST, int TM>
__global__ __launch_bounds__(256) void hgemm(const _Float16* __restrict__ A,
                                             const _Float16* __restrict__ B,
                                             float* __restrict__ Cf,
                                             _Float16* Ch,
                                             const _Float16* AUXh,
                                             _Float16* Cq,
                                             _Float16* Ck,
                                             _Float16* Cv,
                                             int M, int N, int K) {
    constexpr int WN = (TM == 128) ? 2 : 4;
    constexpr int CW = 128 / WN;
    constexpr int FN = CW / 16;
    __shared__ __align__(16) _Float16 As[2][TM * 32];
    __shared__ __align__(16) _Float16 Bs[2][128 * 32];
    const int tid = threadIdx.x;
    const int lane = tid & 63;
    const int wave = tid >> 6;
    const int wr = (TM == 128) ? (wave >> 1) : 0;
    const int wc = (TM == 128) ? (wave & 1) : wave;
    const int l15 = lane & 15, g = lane >> 4;

    const int gm = M / TM, gn = N >> 7, nwg = gm * gn;
    const int orig = blockIdx.x;
    const int q8 = nwg >> 3, r8 = nwg & 7, xcd = orig & 7, j8 = orig >> 3;
    const int wgid = (xcd < r8 ? xcd * (q8 + 1) : r8 * (q8 + 1) + (xcd - r8) * q8) + j8;
    const int bm = MFAST ? (wgid % gm) : (wgid / gn);
    const int bn = MFAST ? (wgid / gm) : (wgid % gn);
    const int m0 = bm * TM, n0 = bn * 128;

    const int offA0 = wave * (TM * 16) + lane * 16;
    const int offA1 = offA0 + 1024;
    const int rA0 = offA0 >> 6, kA0 = offA0 & 63;
    const int rA1 = offA1 >> 6, kA1 = offA1 & 63;
    const int offB0 = wave * 2048 + lane * 16;
    const int offB1 = offB0 + 1024;
    const int rB0 = offB0 >> 6, kB0 = offB0 & 63;
    const int rB1 = offB1 >> 6, kB1 = offB1 & 63;
    const char* gA0 = (const char*)(A + (size_t)(m0 + rA0) * K) + kA0;
    const char* gA1 = (const char*)(A + (size_t)(m0 + rA1) * K) + kA1;
    const char* gB0 = (const char*)(B + (size_t)(n0 + rB0) * K) + kB0;
    const char* gB1 = (const char*)(B + (size_t)(n0 + rB1) * K) + kB1;

#define STAGE(buf)                                                     \
    do {                                                               \
        gload16(gA0, (char*)As[buf] + offA0);                          \
        if constexpr (TM == 128) gload16(gA1, (char*)As[buf] + offA1); \
        gload16(gB0, (char*)Bs[buf] + offB0);                          \
        gload16(gB1, (char*)Bs[buf] + offB1);                          \
        gA0 += 64; gA1 += 64; gB0 += 64; gB1 += 64;                    \
    } while (0)

    floatx4 acc[4][FN];
#pragma unroll
    for (int i = 0; i < 4; i++)
#pragma unroll
        for (int j = 0; j < FN; j++) acc[i][j] = 0;

    STAGE(0);
    __syncthreads();
    int cur = 0;
    for (int kk = 0; kk < K; kk += 32) {
        if (kk + 32 < K) STAGE(cur ^ 1);
        half8 aF[4], bF[FN];
#pragma unroll
        for (int i = 0; i < 4; i++)
            aF[i] = *(const half8*)&As[cur][(wr * 64 + i * 16 + l15) * 32 + g * 8];
#pragma unroll
        for (int j = 0; j < FN; j++)
            bF[j] = *(const half8*)&Bs[cur][(wc * CW + j * 16 + l15) * 32 + g * 8];
#pragma unroll
        for (int i = 0; i < 4; i++)
#pragma unroll
            for (int j = 0; j < FN; j++)
                acc[i][j] = __builtin_amdgcn_mfma_f32_16x16x32_f16(aF[i], bF[j], acc[i][j], 0, 0, 0);
        __syncthreads();
        cur ^= 1;
    }
#undef STAGE

    const int rb = m0 + wr * 64 + g * 4;
    const int cb = n0 + wc * CW + l15;
    if (EPI == 4) {
        const int sel = n0 >> 10;
        _Float16* Cx = sel == 0 ? Cq : (sel == 1 ? Ck : Cv);
        const int cb0 = cb - sel * 1024;
#pragma unroll
        for (int i = 0; i < 4; i++) {
#pragma unroll
            for (int e = 0; e < 4; e++) {
                const int row = rb + i * 16 + e;
                const int pos = row & (S_SZ - 1);
#pragma unroll
                for (int j = 0; j < FN; j++) {
                    float v = acc[i][j][e];
                    const int col = cb0 + j * 16;
                    if (sel < 2) {
                        const float pp = __shfl_xor(v, 1, 64);
                        const int pi = (col & 63) >> 1;
                        const float invf = exp2f((float)pi * -0.41524101186f);
                        float sn, cs;
                        sincosf((float)pos * invf, &sn, &cs);
                        v = (col & 1) ? (pp * sn + v * cs) : (v * cs - pp * sn);
                    }
                    Cx[(size_t)row * 1024 + col] = (_Float16)v;
                }
            }
        }
        return;
    }
#pragma unroll
    for (int i = 0; i < 4; i++) {
#pragma unroll
        for (int e = 0; e < 4; e++) {
            const int row = rb + i * 16 + e;
#pragma unroll
            for (int j = 0; j < FN; j++) {
                const float v = acc[i][j][e];
                const int col = cb + j * 16;
                if (EPI == 0) {
                    Cf[(size_t)row * N + col] = v;
                } else if (EPI == 1) {
                    Cf[(size_t)row * N + col] += v;
                } else if (EPI == 2) {
                    Ch[(size_t)row * N + col] =
                        (_Float16)(v / (1.0f + __expf(-v)));
                } else if (EPI == 3) {
                    const size_t idx = (size_t)row * N + col;
                    Ch[idx] = (_Float16)((float)AUXh[idx] * v);
                }
            }
        }
    }
}

// ---------------------------------------------------------------------------
// Fused SwiGLU GEMM: out[M,F] = swish(A@B1^T) * (A@B3^T), fp16 out.
// ---------------------------------------------------------------------------
__global__ __launch_bounds__(256) void hgemm_ff(const _Float16* __restrict__ A,
                                                const _Float16* __restrict__ B1,
                                                const _Float16* __restrict__ B3,
                                                _Float16* __restrict__ Ch,
                                                int M, int N, int K) {
    __shared__ __align__(16) _Float16 As[2][64 * 32];
    __shared__ __align__(16) _Float16 Bs1[2][128 * 32];
    __shared__ __align__(16) _Float16 Bs3[2][128 * 32];
    const int tid = threadIdx.x;
    const int lane = tid & 63;
    const int wave = tid >> 6;
    const int l15 = lane & 15, g = lane >> 4;

    const int gm = M >> 6, gn = N >> 7, nwg = gm * gn;
    const int orig = blockIdx.x;
    const int q8 = nwg >> 3, r8 = nwg & 7, xcd = orig & 7, j8 = orig >> 3;
    const int wgid = (xcd < r8 ? xcd * (q8 + 1) : r8 * (q8 + 1) + (xcd - r8) * q8) + j8;
    const int bm = wgid % gm, bn = wgid / gm;
    const int m0 = bm * 64, n0 = bn * 128;

    const int offA = wave * 1024 + lane * 16;
    const int rA = offA >> 6, kA = offA & 63;
    const int offB0 = wave * 2048 + lane * 16;
    const int offB1 = offB0 + 1024;
    const int rB0 = offB0 >> 6, kB0 = offB0 & 63;
    const int rB1 = offB1 >> 6, kB1 = offB1 & 63;
    const char* gA  = (const char*)(A  + (size_t)(m0 + rA) * K) + kA;
    const char* gB10 = (const char*)(B1 + (size_t)(n0 + rB0) * K) + kB0;
    const char* gB11 = (const char*)(B1 + (size_t)(n0 + rB1) * K) + kB1;
    const char* gB30 = (const char*)(B3 + (size_t)(n0 + rB0) * K) + kB0;
    const char* gB31 = (const char*)(B3 + (size_t)(n0 + rB1) * K) + kB1;

#define STAGEF(buf)                                   \
    do {                                              \
        gload16(gA,   (char*)As[buf]  + offA);        \
        gload16(gB10, (char*)Bs1[buf] + offB0);       \
        gload16(gB11, (char*)Bs1[buf] + offB1);       \
        gload16(gB30, (char*)Bs3[buf] + offB0);       \
        gload16(gB31, (char*)Bs3[buf] + offB1);       \
        gA += 64; gB10 += 64; gB11 += 64;             \
        gB30 += 64; gB31 += 64;                       \
    } while (0)

    floatx4 acc1[4][2], acc3[4][2];
#pragma unroll
    for (int i = 0; i < 4; i++)
#pragma unroll
        for (int j = 0; j < 2; j++) { acc1[i][j] = 0; acc3[i][j] = 0; }

    STAGEF(0);
    __syncthreads();
    int cur = 0;
    for (int kk = 0; kk < K; kk += 32) {
        if (kk + 32 < K) STAGEF(cur ^ 1);
        half8 aF[4], b1F[2], b3F[2];
#pragma unroll
        for (int i = 0; i < 4; i++)
            aF[i] = *(const half8*)&As[cur][(i * 16 + l15) * 32 + g * 8];
#pragma unroll
        for (int j = 0; j < 2; j++) {
            b1F[j] = *(const half8*)&Bs1[cur][(wave * 32 + j * 16 + l15) * 32 + g * 8];
            b3F[j] = *(const half8*)&Bs3[cur][(wave * 32 + j * 16 + l15) * 32 + g * 8];
        }
#pragma unroll
        for (int i = 0; i < 4; i++)
#pragma unroll
            for (int j = 0; j < 2; j++) {
                acc1[i][j] = __builtin_amdgcn_mfma_f32_16x16x32_f16(aF[i], b1F[j], acc1[i][j], 0, 0, 0);
                acc3[i][j] = __builtin_amdgcn_mfma_f32_16x16x32_f16(aF[i], b3F[j], acc3[i][j], 0, 0, 0);
            }
        __syncthreads();
        cur ^= 1;
    }
#undef STAGEF

    const int cb = n0 + wave * 32 + l15;
#pragma unroll
    for (int i = 0; i < 4; i++) {
#pragma unroll
        for (int e = 0; e < 4; e++) {
            const int row = m0 + i * 16 + g * 4 + e;
#pragma unroll
            for (int j = 0; j < 2; j++) {
                const float v1 = acc1[i][j][e];
                const float v3 = acc3[i][j][e];
                const float sw = v1 / (1.0f + __expf(-v1));
                Ch[(size_t)row * N + cb + j * 16] = (_Float16)(sw * v3);
            }
        }
    }
}

// ---------------------------------------------------------------------------
// Per-head V transpose: vh[b,s,h*64+d] -> vt[(b*16+h)*64+d][s]
// ---------------------------------------------------------------------------
__global__ __launch_bounds__(256) void vtrans(const _Float16* __restrict__ vh,
                                              _Float16* __restrict__ vt) {
    __shared__ __align__(16) _Float16 Ls[64][80];
    const int t = threadIdx.x;
    const int s0 = blockIdx.x * 64;
    const int bh = blockIdx.y;
    const int b = bh >> 4, h = bh & 15;
#pragma unroll
    for (int p = 0; p < 2; ++p) {
        const int sl = p * 32 + (t >> 3);
        const int d = (t & 7) * 8;
        *(half8*)&Ls[sl][d] =
            *(const half8*)&vh[((size_t)b * S_SZ + s0 + sl) * D_SZ + h * 64 + d];
    }
    __syncthreads();
#pragma unroll
    for (int p = 0; p < 2; ++p) {
        const int d = p * 32 + (t >> 3);
        const int sc = (t & 7) * 8;
        half8 v;
#pragma unroll
        for (int j = 0; j < 8; ++j) v[j] = Ls[sc + j][d];
        *(half8*)&vt[((size_t)bh * 64 + d) * S_SZ + s0 + sc] = v;
    }
}

// ---------------------------------------------------------------------------
// Split-K MFMA flash attention (causal). Grid (8, B*H, 2); blockIdx.z = par
// selects the parity class of K/V tiles (kt = par, par+2, ...). Each block
// produces normalized partial Ohat (fp16) + per-row (m, l) (fp32); a merge
// kernel combines the two halves. 512 blocks -> 2 blocks/CU -> 2 waves/SIMD
// (vs 1 before): latency-bound softmax/LDS chains overlap across blocks.
// computeTile identical to the verified round-5 kernel.
// ---------------------------------------------------------------------------
__global__ __launch_bounds__(256) void attn_split(const _Float16* __restrict__ qh,
                                                  const _Float16* __restrict__ kh,
                                                  const _Float16* __restrict__ vt,
                                                  _Float16* __restrict__ aop,
                                                  float2* __restrict__ ml) {
    __shared__ __align__(16) _Float16 Ks[2][64 * 64];
    __shared__ __align__(16) _Float16 Vs[2][64 * 64];
    __shared__ __align__(16) _Float16 Ps[4][16][88];
    const int tid = threadIdx.x;
    const int lane = tid & 63, wave = tid >> 6;
    const int l15 = lane & 15, g = lane >> 4;
    const int bx = blockIdx.x;
    const int bh = blockIdx.y;
    const int par = blockIdx.z;           // K/V tile parity class
    const int h = bh & 15;
    const size_t tokb = (size_t)(bh >> 4) * S_SZ;

    const int qt0 = bx, qt1 = 15 - bx;
    const int qb0 = qt0 * 64, qb1 = qt1 * 64;
    const int ktmax = qt1;                // >= 8 > par always

    const int qrow = l15 * 4 + wave;
    half8 qA0[2], qA1[2];
#pragma unroll
    for (int kk = 0; kk < 2; ++kk) {
        qA0[kk] = *(const half8*)&qh[(tokb + qb0 + qrow) * D_SZ + h * 64 + kk * 32 + g * 8];
        qA1[kk] = *(const half8*)&qh[(tokb + qb1 + qrow) * D_SZ + h * 64 + kk * 32 + g * 8];
    }

    floatx4 accO0[4], accO1[4];
#pragma unroll
    for (int s = 0; s < 4; s++) { accO0[s] = 0; accO1[s] = 0; }
    float m0_[4] = {NEG_INF, NEG_INF, NEG_INF, NEG_INF};
    float l0_[4] = {0.0f, 0.0f, 0.0f, 0.0f};
    float m1_[4] = {NEG_INF, NEG_INF, NEG_INF, NEG_INF};
    float l1_[4] = {0.0f, 0.0f, 0.0f, 0.0f};

    const char* KbB = (const char*)(kh + tokb * D_SZ + h * 64);
    const char* VbB = (const char*)(vt + (size_t)bh * 64 * S_SZ);
    const int so0 = wave * 2048 + lane * 16;
    const int so1 = so0 + 1024;
    const int r0 = so0 >> 7, c0 = (so0 >> 4) & 7;
    const int r1 = so1 >> 7, c1 = (so1 >> 4) & 7;
    const int gc0 = ((c0 ^ (r0 & 7)) << 4);
    const int gc1 = ((c1 ^ (r1 & 7)) << 4);

#define STAGEKV(buf, kt)                                                   \
    do {                                                                   \
        const size_t kvr = (size_t)(kt) * 64;                              \
        gload16(KbB + (kvr + r0) * 2048 + gc0, (char*)Ks[buf] + so0);      \
        gload16(KbB + (kvr + r1) * 2048 + gc1, (char*)Ks[buf] + so1);      \
        gload16(VbB + r0 * 2048 + kvr * 2 + gc0, (char*)Vs[buf] + so0);    \
        gload16(VbB + r1 * 2048 + kvr * 2 + gc1, (char*)Vs[buf] + so1);    \
    } while (0)

#define LDSW(arr, rr, cc) \
    (*(const half8*)&(arr)[(rr) * 64 + ((((cc) ^ ((rr) & 7))) << 3)])

    auto computeTile = [&](const half8* qA, floatx4* accO, float* m_, float* l_,
                           int qbase, int kt, bool diag, int buf) {
        const int kv0 = kt * 64;
        floatx4 accS[4];
        __builtin_amdgcn_s_setprio(1);
#pragma unroll
        for (int sub = 0; sub < 4; ++sub) {
            accS[sub] = 0;
#pragma unroll
            for (int kk = 0; kk < 2; ++kk) {
                half8 kB = LDSW(Ks[buf], sub * 16 + l15, kk * 4 + g);
                accS[sub] = __builtin_amdgcn_mfma_f32_16x16x32_f16(qA[kk], kB, accS[sub], 0, 0, 0);
            }
        }
        __builtin_amdgcn_s_setprio(0);
        float sv[4][4];
        float mx[4] = {NEG_INF, NEG_INF, NEG_INF, NEG_INF};
#pragma unroll
        for (int sub = 0; sub < 4; ++sub)
#pragma unroll
            for (int e = 0; e < 4; ++e) {
                float s = accS[sub][e] * 0.125f;
                if (diag && (kv0 + sub * 16 + l15 > qbase + (g * 4 + e) * 4 + wave))
                    s = NEG_INF;
                sv[sub][e] = s;
                mx[e] = fmaxf(mx[e], s);
            }
#pragma unroll
        for (int msk = 1; msk <= 8; msk <<= 1)
#pragma unroll
            for (int e = 0; e < 4; ++e)
                mx[e] = fmaxf(mx[e], __shfl_xor(mx[e], msk, 64));
        float sf[4];
#pragma unroll
        for (int e = 0; e < 4; ++e) {
            const float mn = fmaxf(m_[e], mx[e]);
            sf[e] = __expf(m_[e] - mn);
            m_[e] = mn;
        }
        float rs[4] = {0.0f, 0.0f, 0.0f, 0.0f};
#pragma unroll
        for (int sub = 0; sub < 4; ++sub)
#pragma unroll
            for (int e = 0; e < 4; ++e) {
                const float p = __expf(sv[sub][e] - m_[e]);
                sv[sub][e] = p;
                rs[e] += p;
            }
#pragma unroll
        for (int msk = 1; msk <= 8; msk <<= 1)
#pragma unroll
            for (int e = 0; e < 4; ++e)
                rs[e] += __shfl_xor(rs[e], msk, 64);
#pragma unroll
        for (int e = 0; e < 4; ++e) l_[e] = l_[e] * sf[e] + rs[e];
#pragma unroll
        for (int sub = 0; sub < 4; ++sub)
#pragma unroll
            for (int e = 0; e < 4; ++e) accO[sub][e] *= sf[e];
#pragma unroll
        for (int sub = 0; sub < 4; ++sub)
#pragma unroll
            for (int e = 0; e < 4; ++e)
                Ps[wave][g * 4 + e][sub * 16 + l15] = (_Float16)sv[sub][e];
        half8 aP[2];
        aP[0] = *(const half8*)&Ps[wave][l15][g * 8];
        aP[1] = *(const half8*)&Ps[wave][l15][32 + g * 8];
        __builtin_amdgcn_s_setprio(1);
#pragma unroll
        for (int sub = 0; sub < 4; ++sub)
#pragma unroll
            for (int kk = 0; kk < 2; ++kk) {
                half8 vB = LDSW(Vs[buf], sub * 16 + l15, kk * 4 + g);
                accO[sub] = __builtin_amdgcn_mfma_f32_16x16x32_f16(aP[kk], vB, accO[sub], 0, 0, 0);
            }
        __builtin_amdgcn_s_setprio(0);
    };

    STAGEKV(0, par);
    __syncthreads();
    int cur = 0;
    for (int kt = par; kt <= ktmax; kt += 2) {
        if (kt + 2 <= ktmax) STAGEKV(cur ^ 1, kt + 2);
        computeTile(qA1, accO1, m1_, l1_, qb1, kt, kt == qt1, cur);
        if (kt <= qt0)
            computeTile(qA0, accO0, m0_, l0_, qb0, kt, kt == qt0, cur);
        __syncthreads();
        cur ^= 1;
    }
#undef STAGEKV
#undef LDSW

    // store normalized partials + (m,l). (m,l) uniform across each 16-lane
    // group; lane l15==0 writes. Zero-work tiles (bx=0,par=1,qt0) keep
    // l=0/m=-inf -> weight 0 in merge.
    _Float16* op = aop + (size_t)par * ((size_t)NTOK * D_SZ);
    float2* mlp = ml + (size_t)par * (B_SZ * H_SZ * S_SZ);
#pragma unroll
    for (int e = 0; e < 4; ++e) {
        const int rr = (g * 4 + e) * 4 + wave;
        const float i1 = l1_[e] > 0.0f ? 1.0f / l1_[e] : 0.0f;
        const float i0 = l0_[e] > 0.0f ? 1.0f / l0_[e] : 0.0f;
#pragma unroll
        for (int sub = 0; sub < 4; ++sub) {
            op[(tokb + qb1 + rr) * D_SZ + h * 64 + sub * 16 + l15] =
                (_Float16)(accO1[sub][e] * i1);
            op[(tokb + qb0 + rr) * D_SZ + h * 64 + sub * 16 + l15] =
                (_Float16)(accO0[sub][e] * i0);
        }
        if (l15 == 0) {
            mlp[bh * S_SZ + qb1 + rr] = float2{m1_[e], l1_[e]};
            mlp[bh * S_SZ + qb0 + rr] = float2{m0_[e], l0_[e]};
        }
    }
}

// ---------------------------------------------------------------------------
// Flash split-K merge: ao = (w0*Ohat0 + w1*Ohat1)/(w0+w1), wi = li*e^(mi-m).
// One block per token row; thread t handles 4 cols (head h = col>>6).
// ---------------------------------------------------------------------------
__global__ __launch_bounds__(256) void attn_merge(const _Float16* __restrict__ aop,
                                                  const float2* __restrict__ ml,
                                                  _Float16* __restrict__ ao) {
    const int row = blockIdx.x;
    const int t = threadIdx.x;
    const int col = t * 4;
    const int h = col >> 6;
    const int b = row >> 10, s = row & (S_SZ - 1);
    const int bh = b * H_SZ + h;
    const float2 v0 = ml[bh * S_SZ + s];
    const float2 v1 = ml[B_SZ * H_SZ * S_SZ + bh * S_SZ + s];
    const float m = fmaxf(v0.x, v1.x);
    const float w0 = v0.y * __expf(v0.x - m);
    const float w1 = v1.y * __expf(v1.x - m);
    const float inv = 1.0f / (w0 + w1);
    const float a0 = w0 * inv, a1 = w1 * inv;
    const size_t base = (size_t)row * D_SZ + col;
    const half4 x0 = *(const half4*)(aop + base);
    const half4 x1 = *(const half4*)(aop + (size_t)NTOK * D_SZ + base);
    half4 o;
#pragma unroll
    for (int j = 0; j < 4; ++j)
        o[j] = (_Float16)(a0 * (float)x0[j] + a1 * (float)x1[j]);
    *(half4*)(ao + base) = o;
}

// ---------------------------------------------------------------------------
// Host-side launch
// ---------------------------------------------------------------------------
extern "C" void kernel_launch(void* const* d_in, const int* in_sizes, int n_in,
                              void* d_out, int out_size, void* d_ws, size_t ws_size,
                              hipStream_t stream) {
    const int*   token_ids  = (const int*)d_in[0];
    const float* tok_emb    = (const float*)d_in[1];
    const float* lm_head_w  = (const float*)d_in[2];
    const float* ln_final_w = (const float*)d_in[3];
    const float* q_w        = (const float*)d_in[4];
    const float* k_w        = (const float*)d_in[5];
    const float* v_w        = (const float*)d_in[6];
    const float* o_w        = (const float*)d_in[7];
    const float* ln1_w      = (const float*)d_in[8];
    const float* ln2_w      = (const float*)d_in[9];
    const float* w1         = (const float*)d_in[10];
    const float* w2         = (const float*)d_in[11];
    const float* w3         = (const float*)d_in[12];
    float* out = (float*)d_out;

    char* W = (char*)d_ws;
    const size_t MB = 1u << 20;
    float*    x    = (float*)(W + 0);           // 8 MB
    _Float16* h    = (_Float16*)(W + 8 * MB);   // 4 MB
    _Float16* ao   = (_Float16*)(W + 12 * MB);  // 4 MB
    _Float16* wq   = (_Float16*)(W + 16 * MB);  // 8 MB: q/k/v/o contiguous
    _Float16* wo   = wq + 3 * (1u << 20);
    _Float16* ww1  = (_Float16*)(W + 24 * MB);  // 24 MB: w1/w3/w2 contiguous
    _Float16* ww3  = ww1 + (size_t)F_SZ * D_SZ;
    _Float16* ww2  = ww1 + 2 * (size_t)F_SZ * D_SZ;
    _Float16* qh   = (_Float16*)(W + 48 * MB);  // 4 MB
    _Float16* kh   = (_Float16*)(W + 52 * MB);  // 4 MB
    _Float16* vh   = (_Float16*)(W + 56 * MB);  // 4 MB
    _Float16* vt   = (_Float16*)(W + 60 * MB);  // 4 MB
    _Float16* ff1h = (_Float16*)(W + 64 * MB);  // 16 MB -> 80 MB (FFN only)
    _Float16* aop  = (_Float16*)(W + 64 * MB);  // 8 MB, overlaps ff1h (attn only)
    float2*   ml   = (float2*)(W + 72 * MB);    // 512 KB, overlaps ff1h
    _Float16* whead = (_Float16*)(W + 24 * MB); // 62.5 MB, overlaps dead ww*/ff*

    embed_kernel<<<NTOK, 256, 0, stream>>>(token_ids, tok_emb, x);

    const int nDD8 = D_SZ * D_SZ / 8;     // 131072
    const int nFD8 = F_SZ * D_SZ / 8;     // 524288
    const int nCNV = 4 * nDD8 + 3 * nFD8; // 2097152
    const dim3 gPRE1(NTOK + nCNV / 256);              // 10240
    const dim3 gQKV(3 * D_SZ / 128 * (NTOK / 128));   // 384
    const dim3 gD64(D_SZ / 128 * (NTOK / 64));        // 256 (TM=64)
    const dim3 gFF(F_SZ / 128 * (NTOK / 64));         // 1024 (fused swiglu)
    const dim3 gATT(S_SZ / 128, B_SZ * H_SZ, 2);      // (8,32,2) split-K halves
    const dim3 gVT(S_SZ / 64, B_SZ * H_SZ);

    for (int l = 0; l < L_SZ; l++) {
        const size_t oDD = (size_t)l * D_SZ * D_SZ;
        const size_t oFD = (size_t)l * F_SZ * D_SZ;
        prep1<<<gPRE1, 256, 0, stream>>>(x, ln1_w + (size_t)l * D_SZ, h,
                                         q_w + oDD, k_w + oDD, v_w + oDD, o_w + oDD,
                                         w1 + oFD, w3 + oFD, w2 + oFD,
                                         wq, nDD8, nFD8);
        hgemm<4, true, 128><<<gQKV, 256, 0, stream>>>(h, wq, nullptr, nullptr, nullptr,
                                                      qh, kh, vh, NTOK, 3 * D_SZ, D_SZ);
        vtrans<<<gVT, 256, 0, stream>>>(vh, vt);
        attn_split<<<gATT, 256, 0, stream>>>(qh, kh, vt, aop, ml);
        attn_merge<<<NTOK, 256, 0, stream>>>(aop, ml, ao);
        hgemm<1, false, 64><<<gD64, 256, 0, stream>>>(ao, wo, x, nullptr, nullptr,
                                                      nullptr, nullptr, nullptr, NTOK, D_SZ, D_SZ);
        rmsnorm_kernel<<<NTOK, 256, 0, stream>>>(x, ln2_w + (size_t)l * D_SZ, h);
        hgemm_ff<<<gFF, 256, 0, stream>>>(h, ww1, ww3, ff1h, NTOK, F_SZ, D_SZ);
        hgemm<1, false, 64><<<gD64, 256, 0, stream>>>(ff1h, ww2, x, nullptr, nullptr,
                                                      nullptr, nullptr, nullptr, NTOK, D_SZ, F_SZ);
    }
    const int nVD8 = V_SZ * D_SZ / 8;                 // 4096000
    prep2<<<NTOK + nVD8 / 256, 256, 0, stream>>>(x, ln_final_w, h, lm_head_w, whead);
    const dim3 gOUT(V_SZ / 256 * (NTOK / 256));       // 1000 (256^2, 8-phase)
    hgemm8p<true><<<gOUT, 512, 0, stream>>>(h, whead, out, NTOK, V_SZ, D_SZ);
}

// Round 12
// 1054.588 us; speedup vs baseline: 1.1517x; 1.1205x over previous
//
#include <hip/hip_runtime.h>
#include <math.h>

// Problem constants (from reference)
#define V_SZ 32000
#define D_SZ 1024
#define H_SZ 16
#define L_SZ 4
#define F_SZ 4096
#define S_SZ 1024
#define B_SZ 2
#define DK 64              // D/H
#define NTOK (B_SZ * S_SZ) // 2048
#define NEG_INF -3.0e38f

typedef _Float16 half8 __attribute__((ext_vector_type(8)));
typedef _Float16 half4 __attribute__((ext_vector_type(4)));
typedef float floatx4 __attribute__((ext_vector_type(4)));

// async global->LDS, 16B per lane; lds dest is wave-uniform base + lane*16.
__device__ __forceinline__ void gload16(const void* g, void* l) {
    __builtin_amdgcn_global_load_lds(
        (const __attribute__((address_space(1))) unsigned int*)g,
        (__attribute__((address_space(3))) unsigned int*)l, 16, 0, 0);
}

// ---------------------------------------------------------------------------
// prep1: fused rmsnorm (blocks [0,NTOK)) + 7-matrix f2h (rest).
// ---------------------------------------------------------------------------
__global__ __launch_bounds__(256) void prep1(const float* __restrict__ x,
                                             const float* __restrict__ lnw,
                                             _Float16* __restrict__ hout,
                                             const float* __restrict__ sq,
                                             const float* __restrict__ sk,
                                             const float* __restrict__ sv,
                                             const float* __restrict__ so,
                                             const float* __restrict__ s1,
                                             const float* __restrict__ s3,
                                             const float* __restrict__ s2,
                                             _Float16* __restrict__ d,
                                             int nDD8, int nFD8) {
    const int tid = threadIdx.x;
    if (blockIdx.x < NTOK) {
        const int row = blockIdx.x;
        const float4 v = ((const float4*)(x + (size_t)row * D_SZ))[tid];
        float ss = v.x * v.x + v.y * v.y + v.z * v.z + v.w * v.w;
#pragma unroll
        for (int off = 32; off > 0; off >>= 1) ss += __shfl_down(ss, off, 64);
        __shared__ float red[4];
        if ((tid & 63) == 0) red[tid >> 6] = ss;
        __syncthreads();
        const float tot = red[0] + red[1] + red[2] + red[3];
        const float inv = 1.0f / (sqrtf(tot * (1.0f / (float)D_SZ)) + 1e-5f);
        const float4 wv = ((const float4*)lnw)[tid];
        half4 o = {(_Float16)(v.x * inv * wv.x), (_Float16)(v.y * inv * wv.y),
                   (_Float16)(v.z * inv * wv.z), (_Float16)(v.w * inv * wv.w)};
        ((half4*)(hout + (size_t)row * D_SZ))[tid] = o;
        return;
    }
    const int i = (blockIdx.x - NTOK) * 256 + tid;
    const float* s;
    int off;
    if (i < 4 * nDD8) {
        const int sel = i / nDD8;
        off = i - sel * nDD8;
        s = sel == 0 ? sq : (sel == 1 ? sk : (sel == 2 ? sv : so));
    } else {
        const int j = i - 4 * nDD8;
        const int sel = j / nFD8;
        off = j - sel * nFD8;
        s = sel == 0 ? s1 : (sel == 1 ? s3 : s2);
    }
    const float4 a = ((const float4*)s)[2 * off];
    const float4 b = ((const float4*)s)[2 * off + 1];
    half8 hv = {(_Float16)a.x, (_Float16)a.y, (_Float16)a.z, (_Float16)a.w,
                (_Float16)b.x, (_Float16)b.y, (_Float16)b.z, (_Float16)b.w};
    ((half8*)d)[i] = hv;
}

// ---------------------------------------------------------------------------
// prep2: fused final rmsnorm + lm_head f2h.
// ---------------------------------------------------------------------------
__global__ __launch_bounds__(256) void prep2(const float* __restrict__ x,
                                             const float* __restrict__ lnw,
                                             _Float16* __restrict__ hout,
                                             const float* __restrict__ win,
                                             _Float16* __restrict__ wout) {
    const int tid = threadIdx.x;
    if (blockIdx.x < NTOK) {
        const int row = blockIdx.x;
        const float4 v = ((const float4*)(x + (size_t)row * D_SZ))[tid];
        float ss = v.x * v.x + v.y * v.y + v.z * v.z + v.w * v.w;
#pragma unroll
        for (int off = 32; off > 0; off >>= 1) ss += __shfl_down(ss, off, 64);
        __shared__ float red[4];
        if ((tid & 63) == 0) red[tid >> 6] = ss;
        __syncthreads();
        const float tot = red[0] + red[1] + red[2] + red[3];
        const float inv = 1.0f / (sqrtf(tot * (1.0f / (float)D_SZ)) + 1e-5f);
        const float4 wv = ((const float4*)lnw)[tid];
        half4 o = {(_Float16)(v.x * inv * wv.x), (_Float16)(v.y * inv * wv.y),
                   (_Float16)(v.z * inv * wv.z), (_Float16)(v.w * inv * wv.w)};
        ((half4*)(hout + (size_t)row * D_SZ))[tid] = o;
        return;
    }
    const int i = (blockIdx.x - NTOK) * 256 + tid;
    const float4 a = ((const float4*)win)[2 * i];
    const float4 b = ((const float4*)win)[2 * i + 1];
    half8 hv = {(_Float16)a.x, (_Float16)a.y, (_Float16)a.z, (_Float16)a.w,
                (_Float16)b.x, (_Float16)b.y, (_Float16)b.z, (_Float16)b.w};
    ((half8*)wout)[i] = hv;
}

// ---------------------------------------------------------------------------
// Embedding gather (fp32)
// ---------------------------------------------------------------------------
__global__ __launch_bounds__(256) void embed_kernel(const int* __restrict__ ids,
                                                    const float* __restrict__ emb,
                                                    float* __restrict__ x) {
    const int row = blockIdx.x;
    const int id = ids[row];
    const float4* src = (const float4*)(emb + (size_t)id * D_SZ);
    float4* dst = (float4*)(x + (size_t)row * D_SZ);
    dst[threadIdx.x] = src[threadIdx.x];
}

// ---------------------------------------------------------------------------
// RMSNorm: fp32 in, fp16 out (standalone, used for ln2)
// ---------------------------------------------------------------------------
__global__ __launch_bounds__(256) void rmsnorm_kernel(const float* __restrict__ x,
                                                      const float* __restrict__ w,
                                                      _Float16* __restrict__ out) {
    const int row = blockIdx.x;
    const int tid = threadIdx.x;
    const float4 v = ((const float4*)(x + (size_t)row * D_SZ))[tid];
    float ss = v.x * v.x + v.y * v.y + v.z * v.z + v.w * v.w;
#pragma unroll
    for (int off = 32; off > 0; off >>= 1) ss += __shfl_down(ss, off, 64);
    __shared__ float red[4];
    if ((tid & 63) == 0) red[tid >> 6] = ss;
    __syncthreads();
    const float tot = red[0] + red[1] + red[2] + red[3];
    const float inv = 1.0f / (sqrtf(tot * (1.0f / (float)D_SZ)) + 1e-5f);
    const float4 wv = ((const float4*)w)[tid];
    half4 o = {(_Float16)(v.x * inv * wv.x), (_Float16)(v.y * inv * wv.y),
               (_Float16)(v.z * inv * wv.z), (_Float16)(v.w * inv * wv.w)};
    ((half4*)(out + (size_t)row * D_SZ))[tid] = o;
}

// ---------------------------------------------------------------------------
// 8-phase deep-pipelined 256x256 MFMA fp16 GEMM (NT). Counted vmcnt(4) per
// tile boundary; XOR swizzle chunk ^= (row>>1)&3 (0-conflict, verified r10).
// Used for lm_head. Schedule frozen.
// ---------------------------------------------------------------------------
template <bool MFAST>
__global__ __launch_bounds__(512) void hgemm8p(const _Float16* __restrict__ A,
                                               const _Float16* __restrict__ B,
                                               float* __restrict__ Cf,
                                               int M, int N, int K) {
    __shared__ __align__(16) _Float16 As[2][2][256 * 32];
    __shared__ __align__(16) _Float16 Bs[2][2][256 * 32];
    const int tid = threadIdx.x;
    const int lane = tid & 63, wave = tid >> 6;
    const int wm = wave >> 2, wn = wave & 3;
    const int l15 = lane & 15, g = lane >> 4;

    const int gm = M >> 8, gn = N >> 8, nwg = gm * gn;
    const int orig = blockIdx.x;
    const int q8 = nwg >> 3, r8 = nwg & 7, xcd = orig & 7, j8 = orig >> 3;
    const int wgid = (xcd < r8 ? xcd * (q8 + 1) : r8 * (q8 + 1) + (xcd - r8) * q8) + j8;
    const int bm = MFAST ? (wgid % gm) : (wgid / gn);
    const int bn = MFAST ? (wgid / gm) : (wgid % gn);
    const int m0 = bm << 8, n0 = bn << 8;

    const int rowS = tid >> 2;
    const int srcC = ((tid & 3) ^ ((rowS >> 1) & 3)) << 4;
    const size_t Kb = (size_t)K * 2;
    const char* gA = (const char*)A + (size_t)(m0 + rowS) * Kb + srcC;
    const char* gB = (const char*)B + (size_t)(n0 + rowS) * Kb + srcC;
    const size_t g128 = 128 * Kb;

#define STA(ks, t, buf) do {                                              \
        const char* _s = gA + (size_t)(t) * 128 + (ks) * 64;              \
        char* _d = (char*)&As[buf][ks][0];                                \
        gload16(_s, _d + tid * 16);                                       \
        gload16(_s + g128, _d + 8192 + tid * 16);                         \
    } while (0)
#define STB(ks, t, buf) do {                                              \
        const char* _s = gB + (size_t)(t) * 128 + (ks) * 64;              \
        char* _d = (char*)&Bs[buf][ks][0];                                \
        gload16(_s, _d + tid * 16);                                       \
        gload16(_s + g128, _d + 8192 + tid * 16);                         \
    } while (0)

    half8 aF[8], bF[2];
#define READA(buf, ks) do {                                               \
        _Pragma("unroll")                                                 \
        for (int i = 0; i < 8; i++) {                                     \
            const int R = wm * 128 + i * 16 + l15;                        \
            aF[i] = *(const half8*)((const char*)&As[buf][ks][0] +        \
                                    R * 64 + ((g ^ ((R >> 1) & 3)) << 4));\
        }                                                                 \
    } while (0)
#define READB(buf, ks, nh) do {                                           \
        _Pragma("unroll")                                                 \
        for (int jj = 0; jj < 2; jj++) {                                  \
            const int R = wn * 64 + ((nh) * 2 + jj) * 16 + l15;           \
            bF[jj] = *(const half8*)((const char*)&Bs[buf][ks][0] +       \
                                     R * 64 + ((g ^ ((R >> 1) & 3)) << 4));\
        }                                                                 \
    } while (0)
#define MFMA16(nh) do {                                                   \
        __builtin_amdgcn_s_setprio(1);                                    \
        _Pragma("unroll")                                                 \
        for (int i = 0; i < 8; i++) {                                     \
            acc[i][(nh) * 2 + 0] = __builtin_amdgcn_mfma_f32_16x16x32_f16(\
                aF[i], bF[0], acc[i][(nh) * 2 + 0], 0, 0, 0);             \
            acc[i][(nh) * 2 + 1] = __builtin_amdgcn_mfma_f32_16x16x32_f16(\
                aF[i], bF[1], acc[i][(nh) * 2 + 1], 0, 0, 0);             \
        }                                                                 \
        __builtin_amdgcn_s_setprio(0);                                    \
    } while (0)
#define FENCE_MID() do {                                                  \
        __builtin_amdgcn_s_barrier();                                     \
        asm volatile("s_waitcnt lgkmcnt(0)" ::: "memory");                \
        __builtin_amdgcn_sched_barrier(0);                                \
    } while (0)

    floatx4 acc[8][4];
#pragma unroll
    for (int i = 0; i < 8; i++)
#pragma unroll
        for (int j = 0; j < 4; j++) acc[i][j] = 0;

    const int nt = K >> 6;
    STA(0, 0, 0); STB(0, 0, 0); STA(1, 0, 0); STB(1, 0, 0);
    STA(0, 1, 1); STB(0, 1, 1);

    for (int t = 0; t < nt; ++t) {
        const int buf = t & 1, nbuf = buf ^ 1;
        if (t == nt - 1) asm volatile("s_waitcnt vmcnt(0)" ::: "memory");
        else             asm volatile("s_waitcnt vmcnt(4)" ::: "memory");
        __builtin_amdgcn_s_barrier();
        READA(buf, 0); READB(buf, 0, 0);
        if (t + 1 < nt) STA(1, t + 1, nbuf);
        FENCE_MID();
        MFMA16(0);
        __builtin_amdgcn_s_barrier();
        READB(buf, 0, 1);
        if (t + 1 < nt) STB(1, t + 1, nbuf);
        FENCE_MID();
        MFMA16(1);
        __builtin_amdgcn_s_barrier();
        READA(buf, 1); READB(buf, 1, 0);
        if (t + 2 < nt) STA(0, t + 2, buf);
        FENCE_MID();
        MFMA16(0);
        __builtin_amdgcn_s_barrier();
        READB(buf, 1, 1);
        if (t + 2 < nt) STB(0, t + 2, buf);
        FENCE_MID();
        MFMA16(1);
        __builtin_amdgcn_s_barrier();
    }
#undef STA
#undef STB
#undef READA
#undef READB
#undef MFMA16
#undef FENCE_MID

#pragma unroll
    for (int i = 0; i < 8; i++) {
#pragma unroll
        for (int e = 0; e < 4; e++) {
            const int row = m0 + wm * 128 + i * 16 + g * 4 + e;
#pragma unroll
            for (int j = 0; j < 4; j++) {
                const int col = n0 + wn * 64 + j * 16 + l15;
                Cf[(size_t)row * N + col] = acc[i][j][e];
            }
        }
    }
}

// ---------------------------------------------------------------------------
// MFMA fp16 GEMM (NT): C[M,N] = A[M,K] * B[N,K]^T, fp32 accumulate.
// Tile TM x 128, BK=32, 4 waves. 2-phase prefetch, double-buffered LDS.
// SPLITK: blocks pair up over K halves; EPI=1 then uses atomicAdd (the
// residual-add semantics make partial accumulation exact).
// EPI: 0 = Cf store; 1 = Cf += (atomic when SPLITK>1); 2 = Ch = swish(v);
//      3 = Ch = AUXh * v; 4 = qkv split store with fused RoPE on q,k and
//      fused per-head transpose for v (writes vt[b*1024+col][s])
// ---------------------------------------------------------------------------
template <int EPI, bool MFAST, int TM, int SPLITK>
__global__ __launch_bounds__(256) void hgemm(const _Float16* __restrict__ A,
                                             const _Float16* __restrict__ B,
                                             float* __restrict__ Cf,
                                             _Float16* Ch,
                                             const _Float16* AUXh,
                                             _Float16* Cq,
                                             _Float16* Ck,
                                             _Float16* Cv,
                                             int M, int N, int K) {
    constexpr int WN = (TM == 128) ? 2 : 4;
    constexpr int CW = 128 / WN;
    constexpr int FN = CW / 16;
    __shared__ __align__(16) _Float16 As[2][TM * 32];
    __shared__ __align__(16) _Float16 Bs[2][128 * 32];
    const int tid = threadIdx.x;
    const int lane = tid & 63;
    const int wave = tid >> 6;
    const int wr = (TM == 128) ? (wave >> 1) : 0;
    const int wc = (TM == 128) ? (wave & 1) : wave;
    const int l15 = lane & 15, g = lane >> 4;

    // bijective XCD chunk swizzle (m204) over the full grid incl. split-K
    const int gm = M / TM, gn = N >> 7, nwgT = gm * gn * SPLITK;
    const int orig = blockIdx.x;
    const int q8 = nwgT >> 3, r8 = nwgT & 7, xcd = orig & 7, j8 = orig >> 3;
    const int wgid = (xcd < r8 ? xcd * (q8 + 1) : r8 * (q8 + 1) + (xcd - r8) * q8) + j8;
    const int sk = wgid % SPLITK;
    const int tile = wgid / SPLITK;
    const int bm = MFAST ? (tile % gm) : (tile / gn);
    const int bn = MFAST ? (tile / gm) : (tile % gn);
    const int m0 = bm * TM, n0 = bn * 128;
    const int Kh = K / SPLITK;
    const int kOff = sk * Kh * 2;   // byte offset into the K dim

    const int offA0 = wave * (TM * 16) + lane * 16;
    const int offA1 = offA0 + 1024;
    const int rA0 = offA0 >> 6, kA0 = offA0 & 63;
    const int rA1 = offA1 >> 6, kA1 = offA1 & 63;
    const int offB0 = wave * 2048 + lane * 16;
    const int offB1 = offB0 + 1024;
    const int rB0 = offB0 >> 6, kB0 = offB0 & 63;
    const int rB1 = offB1 >> 6, kB1 = offB1 & 63;
    const char* gA0 = (const char*)(A + (size_t)(m0 + rA0) * K) + kA0 + kOff;
    const char* gA1 = (const char*)(A + (size_t)(m0 + rA1) * K) + kA1 + kOff;
    const char* gB0 = (const char*)(B + (size_t)(n0 + rB0) * K) + kB0 + kOff;
    const char* gB1 = (const char*)(B + (size_t)(n0 + rB1) * K) + kB1 + kOff;

#define STAGE(buf)                                                     \
    do {                                                               \
        gload16(gA0, (char*)As[buf] + offA0);                          \
        if constexpr (TM == 128) gload16(gA1, (char*)As[buf] + offA1); \
        gload16(gB0, (char*)Bs[buf] + offB0);                          \
        gload16(gB1, (char*)Bs[buf] + offB1);                          \
        gA0 += 64; gA1 += 64; gB0 += 64; gB1 += 64;                    \
    } while (0)

    floatx4 acc[4][FN];
#pragma unroll
    for (int i = 0; i < 4; i++)
#pragma unroll
        for (int j = 0; j < FN; j++) acc[i][j] = 0;

    STAGE(0);
    __syncthreads();
    int cur = 0;
    for (int kk = 0; kk < Kh; kk += 32) {
        if (kk + 32 < Kh) STAGE(cur ^ 1);
        half8 aF[4], bF[FN];
#pragma unroll
        for (int i = 0; i < 4; i++)
            aF[i] = *(const half8*)&As[cur][(wr * 64 + i * 16 + l15) * 32 + g * 8];
#pragma unroll
        for (int j = 0; j < FN; j++)
            bF[j] = *(const half8*)&Bs[cur][(wc * CW + j * 16 + l15) * 32 + g * 8];
#pragma unroll
        for (int i = 0; i < 4; i++)
#pragma unroll
            for (int j = 0; j < FN; j++)
                acc[i][j] = __builtin_amdgcn_mfma_f32_16x16x32_f16(aF[i], bF[j], acc[i][j], 0, 0, 0);
        __syncthreads();
        cur ^= 1;
    }
#undef STAGE

    const int rb = m0 + wr * 64 + g * 4;
    const int cb = n0 + wc * CW + l15;
    if (EPI == 4) {
        const int sel = n0 >> 10;
        const int cb0 = cb - sel * 1024;
#pragma unroll
        for (int i = 0; i < 4; i++) {
#pragma unroll
            for (int e = 0; e < 4; e++) {
                const int row = rb + i * 16 + e;
                const int pos = row & (S_SZ - 1);
#pragma unroll
                for (int j = 0; j < FN; j++) {
                    float v = acc[i][j][e];
                    const int col = cb0 + j * 16;
                    if (sel < 2) {
                        // fused RoPE: pair partner value lives in lane^1
                        const float pp = __shfl_xor(v, 1, 64);
                        const int pi = (col & 63) >> 1;
                        const float invf = exp2f((float)pi * -0.41524101186f);
                        float sn, cs;
                        sincosf((float)pos * invf, &sn, &cs);
                        v = (col & 1) ? (pp * sn + v * cs) : (v * cs - pp * sn);
                        _Float16* Cx = sel == 0 ? Cq : Ck;
                        Cx[(size_t)row * 1024 + col] = (_Float16)v;
                    } else {
                        // fused per-head V transpose: vt[b*1024+col][s]
                        Cv[(((size_t)(row >> 10) << 10) + col) * S_SZ +
                           (row & (S_SZ - 1))] = (_Float16)v;
                    }
                }
            }
        }
        return;
    }
#pragma unroll
    for (int i = 0; i < 4; i++) {
#pragma unroll
        for (int e = 0; e < 4; e++) {
            const int row = rb + i * 16 + e;
#pragma unroll
            for (int j = 0; j < FN; j++) {
                const float v = acc[i][j][e];
                const int col = cb + j * 16;
                if (EPI == 0) {
                    Cf[(size_t)row * N + col] = v;
                } else if (EPI == 1) {
                    if (SPLITK > 1) atomicAdd(&Cf[(size_t)row * N + col], v);
                    else            Cf[(size_t)row * N + col] += v;
                } else if (EPI == 2) {
                    Ch[(size_t)row * N + col] =
                        (_Float16)(v / (1.0f + __expf(-v)));
                } else if (EPI == 3) {
                    const size_t idx = (size_t)row * N + col;
                    Ch[idx] = (_Float16)((float)AUXh[idx] * v);
                }
            }
        }
    }
}

// ---------------------------------------------------------------------------
// Fused SwiGLU GEMM: out[M,F] = swish(A@B1^T) * (A@B3^T), fp16 out.
// ---------------------------------------------------------------------------
__global__ __launch_bounds__(256) void hgemm_ff(const _Float16* __restrict__ A,
                                                const _Float16* __restrict__ B1,
                                                const _Float16* __restrict__ B3,
                                                _Float16* __restrict__ Ch,
                                                int M, int N, int K) {
    __shared__ __align__(16) _Float16 As[2][64 * 32];
    __shared__ __align__(16) _Float16 Bs1[2][128 * 32];
    __shared__ __align__(16) _Float16 Bs3[2][128 * 32];
    const int tid = threadIdx.x;
    const int lane = tid & 63;
    const int wave = tid >> 6;
    const int l15 = lane & 15, g = lane >> 4;

    const int gm = M >> 6, gn = N >> 7, nwg = gm * gn;
    const int orig = blockIdx.x;
    const int q8 = nwg >> 3, r8 = nwg & 7, xcd = orig & 7, j8 = orig >> 3;
    const int wgid = (xcd < r8 ? xcd * (q8 + 1) : r8 * (q8 + 1) + (xcd - r8) * q8) + j8;
    const int bm = wgid % gm, bn = wgid / gm;
    const int m0 = bm * 64, n0 = bn * 128;

    const int offA = wave * 1024 + lane * 16;
    const int rA = offA >> 6, kA = offA & 63;
    const int offB0 = wave * 2048 + lane * 16;
    const int offB1 = offB0 + 1024;
    const int rB0 = offB0 >> 6, kB0 = offB0 & 63;
    const int rB1 = offB1 >> 6, kB1 = offB1 & 63;
    const char* gA  = (const char*)(A  + (size_t)(m0 + rA) * K) + kA;
    const char* gB10 = (const char*)(B1 + (size_t)(n0 + rB0) * K) + kB0;
    const char* gB11 = (const char*)(B1 + (size_t)(n0 + rB1) * K) + kB1;
    const char* gB30 = (const char*)(B3 + (size_t)(n0 + rB0) * K) + kB0;
    const char* gB31 = (const char*)(B3 + (size_t)(n0 + rB1) * K) + kB1;

#define STAGEF(buf)                                   \
    do {                                              \
        gload16(gA,   (char*)As[buf]  + offA);        \
        gload16(gB10, (char*)Bs1[buf] + offB0);       \
        gload16(gB11, (char*)Bs1[buf] + offB1);       \
        gload16(gB30, (char*)Bs3[buf] + offB0);       \
        gload16(gB31, (char*)Bs3[buf] + offB1);       \
        gA += 64; gB10 += 64; gB11 += 64;             \
        gB30 += 64; gB31 += 64;                       \
    } while (0)

    floatx4 acc1[4][2], acc3[4][2];
#pragma unroll
    for (int i = 0; i < 4; i++)
#pragma unroll
        for (int j = 0; j < 2; j++) { acc1[i][j] = 0; acc3[i][j] = 0; }

    STAGEF(0);
    __syncthreads();
    int cur = 0;
    for (int kk = 0; kk < K; kk += 32) {
        if (kk + 32 < K) STAGEF(cur ^ 1);
        half8 aF[4], b1F[2], b3F[2];
#pragma unroll
        for (int i = 0; i < 4; i++)
            aF[i] = *(const half8*)&As[cur][(i * 16 + l15) * 32 + g * 8];
#pragma unroll
        for (int j = 0; j < 2; j++) {
            b1F[j] = *(const half8*)&Bs1[cur][(wave * 32 + j * 16 + l15) * 32 + g * 8];
            b3F[j] = *(const half8*)&Bs3[cur][(wave * 32 + j * 16 + l15) * 32 + g * 8];
        }
#pragma unroll
        for (int i = 0; i < 4; i++)
#pragma unroll
            for (int j = 0; j < 2; j++) {
                acc1[i][j] = __builtin_amdgcn_mfma_f32_16x16x32_f16(aF[i], b1F[j], acc1[i][j], 0, 0, 0);
                acc3[i][j] = __builtin_amdgcn_mfma_f32_16x16x32_f16(aF[i], b3F[j], acc3[i][j], 0, 0, 0);
            }
        __syncthreads();
        cur ^= 1;
    }
#undef STAGEF

    const int cb = n0 + wave * 32 + l15;
#pragma unroll
    for (int i = 0; i < 4; i++) {
#pragma unroll
        for (int e = 0; e < 4; e++) {
            const int row = m0 + i * 16 + g * 4 + e;
#pragma unroll
            for (int j = 0; j < 2; j++) {
                const float v1 = acc1[i][j][e];
                const float v3 = acc3[i][j][e];
                const float sw = v1 / (1.0f + __expf(-v1));
                Ch[(size_t)row * N + cb + j * 16] = (_Float16)(sw * v3);
            }
        }
    }
}

// ---------------------------------------------------------------------------
// Split-K MFMA flash attention (causal). Grid (8, B*H, 2).
// ---------------------------------------------------------------------------
__global__ __launch_bounds__(256) void attn_split(const _Float16* __restrict__ qh,
                                                  const _Float16* __restrict__ kh,
                                                  const _Float16* __restrict__ vt,
                                                  _Float16* __restrict__ aop,
                                                  float2* __restrict__ ml) {
    __shared__ __align__(16) _Float16 Ks[2][64 * 64];
    __shared__ __align__(16) _Float16 Vs[2][64 * 64];
    __shared__ __align__(16) _Float16 Ps[4][16][88];
    const int tid = threadIdx.x;
    const int lane = tid & 63, wave = tid >> 6;
    const int l15 = lane & 15, g = lane >> 4;
    const int bx = blockIdx.x;
    const int bh = blockIdx.y;
    const int par = blockIdx.z;
    const int h = bh & 15;
    const size_t tokb = (size_t)(bh >> 4) * S_SZ;

    const int qt0 = bx, qt1 = 15 - bx;
    const int qb0 = qt0 * 64, qb1 = qt1 * 64;
    const int ktmax = qt1;

    const int qrow = l15 * 4 + wave;
    half8 qA0[2], qA1[2];
#pragma unroll
    for (int kk = 0; kk < 2; ++kk) {
        qA0[kk] = *(const half8*)&qh[(tokb + qb0 + qrow) * D_SZ + h * 64 + kk * 32 + g * 8];
        qA1[kk] = *(const half8*)&qh[(tokb + qb1 + qrow) * D_SZ + h * 64 + kk * 32 + g * 8];
    }

    floatx4 accO0[4], accO1[4];
#pragma unroll
    for (int s = 0; s < 4; s++) { accO0[s] = 0; accO1[s] = 0; }
    float m0_[4] = {NEG_INF, NEG_INF, NEG_INF, NEG_INF};
    float l0_[4] = {0.0f, 0.0f, 0.0f, 0.0f};
    float m1_[4] = {NEG_INF, NEG_INF, NEG_INF, NEG_INF};
    float l1_[4] = {0.0f, 0.0f, 0.0f, 0.0f};

    const char* KbB = (const char*)(kh + tokb * D_SZ + h * 64);
    const char* VbB = (const char*)(vt + (size_t)bh * 64 * S_SZ);
    const int so0 = wave * 2048 + lane * 16;
    const int so1 = so0 + 1024;
    const int r0 = so0 >> 7, c0 = (so0 >> 4) & 7;
    const int r1 = so1 >> 7, c1 = (so1 >> 4) & 7;
    const int gc0 = ((c0 ^ (r0 & 7)) << 4);
    const int gc1 = ((c1 ^ (r1 & 7)) << 4);

#define STAGEKV(buf, kt)                                                   \
    do {                                                                   \
        const size_t kvr = (size_t)(kt) * 64;                              \
        gload16(KbB + (kvr + r0) * 2048 + gc0, (char*)Ks[buf] + so0);      \
        gload16(KbB + (kvr + r1) * 2048 + gc1, (char*)Ks[buf] + so1);      \
        gload16(VbB + r0 * 2048 + kvr * 2 + gc0, (char*)Vs[buf] + so0);    \
        gload16(VbB + r1 * 2048 + kvr * 2 + gc1, (char*)Vs[buf] + so1);    \
    } while (0)

#define LDSW(arr, rr, cc) \
    (*(const half8*)&(arr)[(rr) * 64 + ((((cc) ^ ((rr) & 7))) << 3)])

    auto computeTile = [&](const half8* qA, floatx4* accO, float* m_, float* l_,
                           int qbase, int kt, bool diag, int buf) {
        const int kv0 = kt * 64;
        floatx4 accS[4];
        __builtin_amdgcn_s_setprio(1);
#pragma unroll
        for (int sub = 0; sub < 4; ++sub) {
            accS[sub] = 0;
#pragma unroll
            for (int kk = 0; kk < 2; ++kk) {
                half8 kB = LDSW(Ks[buf], sub * 16 + l15, kk * 4 + g);
                accS[sub] = __builtin_amdgcn_mfma_f32_16x16x32_f16(qA[kk], kB, accS[sub], 0, 0, 0);
            }
        }
        __builtin_amdgcn_s_setprio(0);
        float sv[4][4];
        float mx[4] = {NEG_INF, NEG_INF, NEG_INF, NEG_INF};
#pragma unroll
        for (int sub = 0; sub < 4; ++sub)
#pragma unroll
            for (int e = 0; e < 4; ++e) {
                float s = accS[sub][e] * 0.125f;
                if (diag && (kv0 + sub * 16 + l15 > qbase + (g * 4 + e) * 4 + wave))
                    s = NEG_INF;
                sv[sub][e] = s;
                mx[e] = fmaxf(mx[e], s);
            }
#pragma unroll
        for (int msk = 1; msk <= 8; msk <<= 1)
#pragma unroll
            for (int e = 0; e < 4; ++e)
                mx[e] = fmaxf(mx[e], __shfl_xor(mx[e], msk, 64));
        float sf[4];
#pragma unroll
        for (int e = 0; e < 4; ++e) {
            const float mn = fmaxf(m_[e], mx[e]);
            sf[e] = __expf(m_[e] - mn);
            m_[e] = mn;
        }
        float rs[4] = {0.0f, 0.0f, 0.0f, 0.0f};
#pragma unroll
        for (int sub = 0; sub < 4; ++sub)
#pragma unroll
            for (int e = 0; e < 4; ++e) {
                const float p = __expf(sv[sub][e] - m_[e]);
                sv[sub][e] = p;
                rs[e] += p;
            }
#pragma unroll
        for (int msk = 1; msk <= 8; msk <<= 1)
#pragma unroll
            for (int e = 0; e < 4; ++e)
                rs[e] += __shfl_xor(rs[e], msk, 64);
#pragma unroll
        for (int e = 0; e < 4; ++e) l_[e] = l_[e] * sf[e] + rs[e];
#pragma unroll
        for (int sub = 0; sub < 4; ++sub)
#pragma unroll
            for (int e = 0; e < 4; ++e) accO[sub][e] *= sf[e];
#pragma unroll
        for (int sub = 0; sub < 4; ++sub)
#pragma unroll
            for (int e = 0; e < 4; ++e)
                Ps[wave][g * 4 + e][sub * 16 + l15] = (_Float16)sv[sub][e];
        half8 aP[2];
        aP[0] = *(const half8*)&Ps[wave][l15][g * 8];
        aP[1] = *(const half8*)&Ps[wave][l15][32 + g * 8];
        __builtin_amdgcn_s_setprio(1);
#pragma unroll
        for (int sub = 0; sub < 4; ++sub)
#pragma unroll
            for (int kk = 0; kk < 2; ++kk) {
                half8 vB = LDSW(Vs[buf], sub * 16 + l15, kk * 4 + g);
                accO[sub] = __builtin_amdgcn_mfma_f32_16x16x32_f16(aP[kk], vB, accO[sub], 0, 0, 0);
            }
        __builtin_amdgcn_s_setprio(0);
    };

    STAGEKV(0, par);
    __syncthreads();
    int cur = 0;
    for (int kt = par; kt <= ktmax; kt += 2) {
        if (kt + 2 <= ktmax) STAGEKV(cur ^ 1, kt + 2);
        computeTile(qA1, accO1, m1_, l1_, qb1, kt, kt == qt1, cur);
        if (kt <= qt0)
            computeTile(qA0, accO0, m0_, l0_, qb0, kt, kt == qt0, cur);
        __syncthreads();
        cur ^= 1;
    }
#undef STAGEKV
#undef LDSW

    _Float16* op = aop + (size_t)par * ((size_t)NTOK * D_SZ);
    float2* mlp = ml + (size_t)par * (B_SZ * H_SZ * S_SZ);
#pragma unroll
    for (int e = 0; e < 4; ++e) {
        const int rr = (g * 4 + e) * 4 + wave;
        const float i1 = l1_[e] > 0.0f ? 1.0f / l1_[e] : 0.0f;
        const float i0 = l0_[e] > 0.0f ? 1.0f / l0_[e] : 0.0f;
#pragma unroll
        for (int sub = 0; sub < 4; ++sub) {
            op[(tokb + qb1 + rr) * D_SZ + h * 64 + sub * 16 + l15] =
                (_Float16)(accO1[sub][e] * i1);
            op[(tokb + qb0 + rr) * D_SZ + h * 64 + sub * 16 + l15] =
                (_Float16)(accO0[sub][e] * i0);
        }
        if (l15 == 0) {
            mlp[bh * S_SZ + qb1 + rr] = float2{m1_[e], l1_[e]};
            mlp[bh * S_SZ + qb0 + rr] = float2{m0_[e], l0_[e]};
        }
    }
}

// ---------------------------------------------------------------------------
// Flash split-K merge.
// ---------------------------------------------------------------------------
__global__ __launch_bounds__(256) void attn_merge(const _Float16* __restrict__ aop,
                                                  const float2* __restrict__ ml,
                                                  _Float16* __restrict__ ao) {
    const int row = blockIdx.x;
    const int t = threadIdx.x;
    const int col = t * 4;
    const int h = col >> 6;
    const int b = row >> 10, s = row & (S_SZ - 1);
    const int bh = b * H_SZ + h;
    const float2 v0 = ml[bh * S_SZ + s];
    const float2 v1 = ml[B_SZ * H_SZ * S_SZ + bh * S_SZ + s];
    const float m = fmaxf(v0.x, v1.x);
    const float w0 = v0.y * __expf(v0.x - m);
    const float w1 = v1.y * __expf(v1.x - m);
    const float inv = 1.0f / (w0 + w1);
    const float a0 = w0 * inv, a1 = w1 * inv;
    const size_t base = (size_t)row * D_SZ + col;
    const half4 x0 = *(const half4*)(aop + base);
    const half4 x1 = *(const half4*)(aop + (size_t)NTOK * D_SZ + base);
    half4 o;
#pragma unroll
    for (int j = 0; j < 4; ++j)
        o[j] = (_Float16)(a0 * (float)x0[j] + a1 * (float)x1[j]);
    *(half4*)(ao + base) = o;
}

// ---------------------------------------------------------------------------
// Host-side launch
// ---------------------------------------------------------------------------
extern "C" void kernel_launch(void* const* d_in, const int* in_sizes, int n_in,
                              void* d_out, int out_size, void* d_ws, size_t ws_size,
                              hipStream_t stream) {
    const int*   token_ids  = (const int*)d_in[0];
    const float* tok_emb    = (const float*)d_in[1];
    const float* lm_head_w  = (const float*)d_in[2];
    const float* ln_final_w = (const float*)d_in[3];
    const float* q_w        = (const float*)d_in[4];
    const float* k_w        = (const float*)d_in[5];
    const float* v_w        = (const float*)d_in[6];
    const float* o_w        = (const float*)d_in[7];
    const float* ln1_w      = (const float*)d_in[8];
    const float* ln2_w      = (const float*)d_in[9];
    const float* w1         = (const float*)d_in[10];
    const float* w2         = (const float*)d_in[11];
    const float* w3         = (const float*)d_in[12];
    float* out = (float*)d_out;

    char* W = (char*)d_ws;
    const size_t MB = 1u << 20;
    float*    x    = (float*)(W + 0);           // 8 MB
    _Float16* h    = (_Float16*)(W + 8 * MB);   // 4 MB
    _Float16* ao   = (_Float16*)(W + 12 * MB);  // 4 MB
    _Float16* wq   = (_Float16*)(W + 16 * MB);  // 8 MB: q/k/v/o contiguous
    _Float16* wo   = wq + 3 * (1u << 20);
    _Float16* ww1  = (_Float16*)(W + 24 * MB);  // 24 MB: w1/w3/w2 contiguous
    _Float16* ww3  = ww1 + (size_t)F_SZ * D_SZ;
    _Float16* ww2  = ww1 + 2 * (size_t)F_SZ * D_SZ;
    _Float16* qh   = (_Float16*)(W + 48 * MB);  // 4 MB
    _Float16* kh   = (_Float16*)(W + 52 * MB);  // 4 MB
    _Float16* vt   = (_Float16*)(W + 56 * MB);  // 4 MB (transposed V, from qkv)
    _Float16* ff1h = (_Float16*)(W + 64 * MB);  // 16 MB -> 80 MB (FFN only)
    _Float16* aop  = (_Float16*)(W + 64 * MB);  // 8 MB, overlaps ff1h (attn only)
    float2*   ml   = (float2*)(W + 72 * MB);    // 512 KB, overlaps ff1h
    _Float16* whead = (_Float16*)(W + 24 * MB); // 62.5 MB, overlaps dead ww*/ff*

    embed_kernel<<<NTOK, 256, 0, stream>>>(token_ids, tok_emb, x);

    const int nDD8 = D_SZ * D_SZ / 8;     // 131072
    const int nFD8 = F_SZ * D_SZ / 8;     // 524288
    const int nCNV = 4 * nDD8 + 3 * nFD8; // 2097152
    const dim3 gPRE1(NTOK + nCNV / 256);              // 10240
    const dim3 gQKV(3 * D_SZ / 128 * (NTOK / 64));    // 768 (TM=64)
    const dim3 gD64sk(D_SZ / 128 * (NTOK / 64) * 2);  // 512 (TM=64, split-K 2)
    const dim3 gFF(F_SZ / 128 * (NTOK / 64));         // 1024 (fused swiglu)
    const dim3 gATT(S_SZ / 128, B_SZ * H_SZ, 2);      // (8,32,2) split-K halves
    for (int l = 0; l < L_SZ; l++) {
        const size_t oDD = (size_t)l * D_SZ * D_SZ;
        const size_t oFD = (size_t)l * F_SZ * D_SZ;
        prep1<<<gPRE1, 256, 0, stream>>>(x, ln1_w + (size_t)l * D_SZ, h,
                                         q_w + oDD, k_w + oDD, v_w + oDD, o_w + oDD,
                                         w1 + oFD, w3 + oFD, w2 + oFD,
                                         wq, nDD8, nFD8);
        hgemm<4, true, 64, 1><<<gQKV, 256, 0, stream>>>(h, wq, nullptr, nullptr, nullptr,
                                                        qh, kh, vt, NTOK, 3 * D_SZ, D_SZ);
        attn_split<<<gATT, 256, 0, stream>>>(qh, kh, vt, aop, ml);
        attn_merge<<<NTOK, 256, 0, stream>>>(aop, ml, ao);
        hgemm<1, false, 64, 2><<<gD64sk, 256, 0, stream>>>(ao, wo, x, nullptr, nullptr,
                                                           nullptr, nullptr, nullptr, NTOK, D_SZ, D_SZ);
        rmsnorm_kernel<<<NTOK, 256, 0, stream>>>(x, ln2_w + (size_t)l * D_SZ, h);
        hgemm_ff<<<gFF, 256, 0, stream>>>(h, ww1, ww3, ff1h, NTOK, F_SZ, D_SZ);
        hgemm<1, false, 64, 2><<<gD64sk, 256, 0, stream>>>(ff1h, ww2, x, nullptr, nullptr,
                                                           nullptr, nullptr, nullptr, NTOK, D_SZ, F_SZ);
    }
    const int nVD8 = V_SZ * D_SZ / 8;                 // 4096000
    prep2<<<NTOK + nVD8 / 256, 256, 0, stream>>>(x, ln_final_w, h, lm_head_w, whead);
    const dim3 gOUT(V_SZ / 256 * (NTOK / 256));       // 1000 (256^2, 8-phase)
    hgemm8p<true><<<gOUT, 512, 0, stream>>>(h, whead, out, NTOK, V_SZ, D_SZ);
}